// Round 1
// 274.397 us; speedup vs baseline: 1.5648x; 1.5648x over previous
//
#include <hip/hip_runtime.h>
#include <hip/hip_bf16.h>

// GAT layer: B=8, N=8 (BN=64 batches), Nodes=512, IF=OF=256.
// MFMA rewrite: both GEMMs (h@W and att@Wh) on v_mfma_f32_16x16x32_bf16
// with split-bf16 (hi+lo) operands for fp32-level accuracy.
//
// Pipeline:
//  K0: detect dtype -> flag in ws
//  KP: W -> Wt[f][k] bf16 hi/lo (transposed for B-fragments)
//  KA: Wh = h@W via MFMA (3-term split). Writes WhT[bn][f][i] bf16 hi/lo,
//      src/dst from fp32 accumulators (shuffle reduce).
//  KB: e=leaky(src_i+dst_j), mask, softmax (8 lanes/row), P -> LDS bf16 hi/lo,
//      out = elu((P@Wh)/rowsum) via MFMA (3-term split).

#define ALPHA 0.2f
#define MASK_VAL -9000000000000000.0f
#define NODES 512
#define FDIM 256
#define BN 64

typedef float  f32x4 __attribute__((ext_vector_type(4)));
typedef int    i32x4 __attribute__((ext_vector_type(4)));
typedef short  s16x8 __attribute__((ext_vector_type(8)));
typedef short  s16x4 __attribute__((ext_vector_type(4)));
typedef __bf16 bf16x8 __attribute__((ext_vector_type(8)));

__device__ __forceinline__ unsigned short f2bfu(float x) {
    __hip_bfloat16 b = __float2bfloat16(x);   // RNE
    unsigned short u; __builtin_memcpy(&u, &b, 2); return u;
}
__device__ __forceinline__ float bfu2f(unsigned short u) {
    unsigned int w = ((unsigned int)u) << 16; return __uint_as_float(w);
}

__device__ __forceinline__ f32x4 mfma16(s16x8 a, s16x8 b, f32x4 c) {
    return __builtin_amdgcn_mfma_f32_16x16x32_bf16(
        __builtin_bit_cast(bf16x8, a), __builtin_bit_cast(bf16x8, b), c, 0, 0, 0);
}

// ---------------- K0: dtype detect ----------------
__global__ __launch_bounds__(256) void detect_kernel(const unsigned short* __restrict__ hraw,
                                                     int* __restrict__ flag)
{
    const int tid = threadIdx.x;
    float m = 0.0f;
    for (int i = tid; i < 16384; i += 256) {
        unsigned int w = ((unsigned int)hraw[i]) << 16;
        float v = __uint_as_float(w);
        v = fabsf(v);
        if (!(v == v)) v = 1e30f;
        m = fmaxf(m, v);
    }
    #pragma unroll
    for (int off = 32; off >= 1; off >>= 1)
        m = fmaxf(m, __shfl_down(m, off));
    __shared__ float red[4];
    if ((tid & 63) == 0) red[tid >> 6] = m;
    __syncthreads();
    if (tid == 0) {
        float mm = fmaxf(fmaxf(red[0], red[1]), fmaxf(red[2], red[3]));
        *flag = (mm > 1e4f) ? 1 : 0;
    }
}

// ---------------- KP: W -> Wt[f][k] bf16 hi/lo ----------------
__global__ __launch_bounds__(256) void prep_w_kernel(
    const void* __restrict__ Wv, const int* __restrict__ flagp,
    short* __restrict__ WtHi, short* __restrict__ WtLo)
{
    const int flag = *flagp;
    __shared__ float tile[16][17];
    const int tx = threadIdx.x & 15, ty = threadIdx.x >> 4;
    const int kk = blockIdx.y * 16 + ty;
    const int f  = blockIdx.x * 16 + tx;
    float v;
    if (flag) v = ((const float*)Wv)[kk * FDIM + f];
    else      v = bfu2f(((const unsigned short*)Wv)[kk * FDIM + f]);
    tile[ty][tx] = v;
    __syncthreads();
    const float x = tile[tx][ty];                 // = W[by*16+tx'][bx*16+ty']
    const int fo = blockIdx.x * 16 + ty;
    const int ko = blockIdx.y * 16 + tx;
    unsigned short h = f2bfu(x);
    WtHi[fo * FDIM + ko] = (short)h;
    WtLo[fo * FDIM + ko] = (short)f2bfu(x - bfu2f(h));  // exact 0 in bf16 mode
}

// ---------------- KA: Wh = h@W (MFMA) + src/dst ----------------
// grid (8, 64), 256 thr = 4 waves. Block: 64 rows x 256 cols, K=256.
// Wave w: rows i0+w*16..+16, 16 col-tiles, acc = 16 x f32x4 (64 VGPR).
// A-frag: lane row = l&15, k = (l>>4)*8..+8  (direct from global h)
// B-frag: lane col = l&15, k = (l>>4)*8..+8  (from Wt[f][k])
__global__ __launch_bounds__(256) void wh_mfma_kernel(
    const void* __restrict__ hv,
    const short* __restrict__ WtHi, const short* __restrict__ WtLo,
    const void* __restrict__ av,
    const int* __restrict__ flagp,
    short* __restrict__ WhTHi, short* __restrict__ WhTLo,
    float* __restrict__ srcv, float* __restrict__ dstv)
{
    const int flag = *flagp;
    const int bn  = blockIdx.y;
    const int i0  = blockIdx.x * 64;
    const int tid = threadIdx.x;
    const int w   = tid >> 6;
    const int l   = tid & 63;
    const int fb  = l & 15;
    const int kg  = (l >> 4) * 8;
    const int arow = i0 + w * 16 + fb;

    f32x4 acc[16];
    #pragma unroll
    for (int t = 0; t < 16; ++t) acc[t] = f32x4{0.f, 0.f, 0.f, 0.f};

    const size_t hbase = ((size_t)bn * NODES + arow) * FDIM;

    if (flag) {
        for (int k0 = 0; k0 < FDIM; k0 += 32) {
            const int kk = k0 + kg;
            const float* hp = (const float*)hv + hbase + kk;
            f32x4 v0 = *(const f32x4*)hp;
            f32x4 v1 = *(const f32x4*)(hp + 4);
            s16x8 ahi, alo;
            #pragma unroll
            for (int e = 0; e < 4; ++e) {
                unsigned short h0 = f2bfu(v0[e]);
                ahi[e]     = (short)h0;
                alo[e]     = (short)f2bfu(v0[e] - bfu2f(h0));
                unsigned short h1 = f2bfu(v1[e]);
                ahi[4 + e] = (short)h1;
                alo[4 + e] = (short)f2bfu(v1[e] - bfu2f(h1));
            }
            #pragma unroll
            for (int ct = 0; ct < 16; ++ct) {
                const int f = ct * 16 + fb;
                const s16x8 bh = *(const s16x8*)(WtHi + f * FDIM + kk);
                const s16x8 bl = *(const s16x8*)(WtLo + f * FDIM + kk);
                acc[ct] = mfma16(ahi, bh, acc[ct]);
                acc[ct] = mfma16(alo, bh, acc[ct]);
                acc[ct] = mfma16(ahi, bl, acc[ct]);
            }
        }
    } else {
        for (int k0 = 0; k0 < FDIM; k0 += 32) {
            const int kk = k0 + kg;
            const s16x8 ahi = *(const s16x8*)((const short*)hv + hbase + kk);
            #pragma unroll
            for (int ct = 0; ct < 16; ++ct) {
                const int f = ct * 16 + fb;
                const s16x8 bh = *(const s16x8*)(WtHi + f * FDIM + kk);
                acc[ct] = mfma16(ahi, bh, acc[ct]);   // inputs exact in bf16 mode
            }
        }
    }

    // Write WhT[bn][f][i] hi/lo.  D layout: row=(l>>4)*4+r, col=ct*16+fb.
    const int r0   = (l >> 4) * 4;
    const int orow = i0 + w * 16 + r0;
    const size_t wbase = (size_t)bn * FDIM * NODES;
    #pragma unroll
    for (int ct = 0; ct < 16; ++ct) {
        const int f = ct * 16 + fb;
        s16x4 hi4, lo4;
        #pragma unroll
        for (int r = 0; r < 4; ++r) {
            float x = acc[ct][r];
            unsigned short h = f2bfu(x);
            hi4[r] = (short)h;
            lo4[r] = (short)f2bfu(x - bfu2f(h));
        }
        *(s16x4*)(WhTHi + wbase + (size_t)f * NODES + orow) = hi4;
        *(s16x4*)(WhTLo + wbase + (size_t)f * NODES + orow) = lo4;
    }

    // src/dst from fp32 accumulators (same precision path as before).
    float a1v[16], a2v[16];
    #pragma unroll
    for (int ct = 0; ct < 16; ++ct) {
        const int f = ct * 16 + fb;
        if (flag) {
            a1v[ct] = ((const float*)av)[f];
            a2v[ct] = ((const float*)av)[FDIM + f];
        } else {
            a1v[ct] = bfu2f(((const unsigned short*)av)[f]);
            a2v[ct] = bfu2f(((const unsigned short*)av)[FDIM + f]);
        }
    }
    #pragma unroll
    for (int r = 0; r < 4; ++r) {
        float s1 = 0.f, s2 = 0.f;
        #pragma unroll
        for (int ct = 0; ct < 16; ++ct) {
            s1 = fmaf(acc[ct][r], a1v[ct], s1);
            s2 = fmaf(acc[ct][r], a2v[ct], s2);
        }
        #pragma unroll
        for (int off = 1; off <= 8; off <<= 1) {
            s1 += __shfl_xor(s1, off);
            s2 += __shfl_xor(s2, off);
        }
        if (fb == 0) {
            srcv[bn * NODES + orow + r] = s1;
            dstv[bn * NODES + orow + r] = s2;
        }
    }
}

// ---------------- KB: softmax + att@Wh (MFMA) + elu ----------------
// grid (16, 64), 256 thr = 4 waves. Block: 32 att rows, K=512, N=256.
// Softmax: wave w owns rows w*8..w*8+8; 8 lanes per row, 64 j's each.
// LDS att hi/lo [32][520] (pad 8 shorts -> 1040B row stride, b128-friendly).
// MFMA: wave w -> col-tiles w*4..w*4+4, 2 row-tiles, acc 2x4 x f32x4.
__global__ __launch_bounds__(256) void attn_mfma_kernel(
    const short* __restrict__ WhTHi, const short* __restrict__ WhTLo,
    const float* __restrict__ srcv, const float* __restrict__ dstv,
    const int* __restrict__ adj, const int* __restrict__ flagp,
    void* __restrict__ out)
{
    const int flag = *flagp;
    const int bn  = blockIdx.y;
    const int i0  = blockIdx.x * 32;
    const int tid = threadIdx.x;
    const int w   = tid >> 6;
    const int l   = tid & 63;

    __shared__ short aHi[32][520];
    __shared__ short aLo[32][520];
    __shared__ float rowinv[32];

    const int lr = w * 8 + (l >> 3);      // local row 0..31
    const int jc = (l & 7) * 64;          // lane's j-chunk
    const float srow = srcv[bn * NODES + i0 + lr];
    const int*   adjrow = adj + (size_t)(i0 + lr) * NODES;
    const float* drow   = dstv + bn * NODES;

    // pass 1: row max (includes MASK_VAL like reference)
    float m = -3.0e38f;
    #pragma unroll
    for (int g = 0; g < 8; ++g) {
        const int j = jc + g * 8;
        const i32x4 q0 = *(const i32x4*)(adjrow + j);
        const i32x4 q1 = *(const i32x4*)(adjrow + j + 4);
        const f32x4 d0 = *(const f32x4*)(drow + j);
        const f32x4 d1 = *(const f32x4*)(drow + j + 4);
        #pragma unroll
        for (int e = 0; e < 4; ++e) {
            float ev = srow + d0[e];
            ev = (ev > 0.f) ? ev : ALPHA * ev;
            m = fmaxf(m, (q0[e] > 0) ? ev : MASK_VAL);
            float ew = srow + d1[e];
            ew = (ew > 0.f) ? ew : ALPHA * ew;
            m = fmaxf(m, (q1[e] > 0) ? ew : MASK_VAL);
        }
    }
    #pragma unroll
    for (int off = 1; off <= 4; off <<= 1) m = fmaxf(m, __shfl_xor(m, off));

    // pass 2: exp, sum, store P hi/lo to LDS
    float s = 0.f;
    #pragma unroll
    for (int g = 0; g < 8; ++g) {
        const int j = jc + g * 8;
        const i32x4 q0 = *(const i32x4*)(adjrow + j);
        const i32x4 q1 = *(const i32x4*)(adjrow + j + 4);
        const f32x4 d0 = *(const f32x4*)(drow + j);
        const f32x4 d1 = *(const f32x4*)(drow + j + 4);
        s16x8 ph, pl;
        #pragma unroll
        for (int e = 0; e < 4; ++e) {
            float ev = srow + d0[e];
            ev = (ev > 0.f) ? ev : ALPHA * ev;
            ev = (q0[e] > 0) ? ev : MASK_VAL;
            float p = __expf(ev - m);      // masked -> 0; all-masked row -> 1
            s += p;
            unsigned short h = f2bfu(p);
            ph[e] = (short)h; pl[e] = (short)f2bfu(p - bfu2f(h));
            float ew = srow + d1[e];
            ew = (ew > 0.f) ? ew : ALPHA * ew;
            ew = (q1[e] > 0) ? ew : MASK_VAL;
            float p2 = __expf(ew - m);
            s += p2;
            unsigned short h2 = f2bfu(p2);
            ph[4 + e] = (short)h2; pl[4 + e] = (short)f2bfu(p2 - bfu2f(h2));
        }
        *(s16x8*)&aHi[lr][j] = ph;
        *(s16x8*)&aLo[lr][j] = pl;
    }
    #pragma unroll
    for (int off = 1; off <= 4; off <<= 1) s += __shfl_xor(s, off);
    if ((l & 7) == 0) rowinv[lr] = 1.0f / s;
    __syncthreads();

    // MFMA phase
    const int fb  = l & 15;
    const int kg  = (l >> 4) * 8;
    const int wct = w * 4;
    const size_t wbase = (size_t)bn * FDIM * NODES;

    f32x4 acc[2][4];
    #pragma unroll
    for (int rt = 0; rt < 2; ++rt)
        #pragma unroll
        for (int c = 0; c < 4; ++c) acc[rt][c] = f32x4{0.f, 0.f, 0.f, 0.f};

    for (int k0 = 0; k0 < NODES; k0 += 32) {
        const int kk = k0 + kg;
        const s16x8 a0h = *(const s16x8*)&aHi[fb][kk];
        const s16x8 a0l = *(const s16x8*)&aLo[fb][kk];
        const s16x8 a1h = *(const s16x8*)&aHi[16 + fb][kk];
        const s16x8 a1l = *(const s16x8*)&aLo[16 + fb][kk];
        #pragma unroll
        for (int c = 0; c < 4; ++c) {
            const int f = (wct + c) * 16 + fb;
            const s16x8 bh = *(const s16x8*)(WhTHi + wbase + (size_t)f * NODES + kk);
            const s16x8 bl = *(const s16x8*)(WhTLo + wbase + (size_t)f * NODES + kk);
            acc[0][c] = mfma16(a0h, bh, acc[0][c]);
            acc[0][c] = mfma16(a0l, bh, acc[0][c]);
            acc[0][c] = mfma16(a0h, bl, acc[0][c]);
            acc[1][c] = mfma16(a1h, bh, acc[1][c]);
            acc[1][c] = mfma16(a1l, bh, acc[1][c]);
            acc[1][c] = mfma16(a1h, bl, acc[1][c]);
        }
    }

    // epilogue: scale by 1/rowsum, elu, store
    const int r0 = (l >> 4) * 4;
    #pragma unroll
    for (int rt = 0; rt < 2; ++rt) {
        float inv[4];
        #pragma unroll
        for (int r = 0; r < 4; ++r) inv[r] = rowinv[rt * 16 + r0 + r];
        #pragma unroll
        for (int c = 0; c < 4; ++c) {
            const int f = (wct + c) * 16 + fb;
            #pragma unroll
            for (int r = 0; r < 4; ++r) {
                float v = acc[rt][c][r] * inv[r];
                v = (v > 0.f) ? v : expm1f(v);
                const size_t o = ((size_t)bn * NODES + i0 + rt * 16 + r0 + r) * FDIM + f;
                if (flag) ((float*)out)[o] = v;
                else      ((unsigned short*)out)[o] = f2bfu(v);
            }
        }
    }
}

extern "C" void kernel_launch(void* const* d_in, const int* in_sizes, int n_in,
                              void* d_out, int out_size, void* d_ws, size_t ws_size,
                              hipStream_t stream)
{
    const void* h   = d_in[0];
    const int*  adj = (const int*)d_in[1];
    const void* W   = d_in[2];
    const void* a   = d_in[3];

    // ws layout:
    //  [0..255]      flag (+pad)
    //  src  fp32     BN*NODES          = 128 KB
    //  dst  fp32     BN*NODES          = 128 KB
    //  WtHi bf16     FDIM*FDIM         = 128 KB
    //  WtLo bf16     FDIM*FDIM         = 128 KB
    //  WhTHi bf16    BN*FDIM*NODES     = 16.78 MB
    //  WhTLo bf16    BN*FDIM*NODES     = 16.78 MB
    //  total ~34.1 MB
    int*   flag  = (int*)d_ws;
    float* srcv  = (float*)d_ws + 64;
    float* dstv  = srcv + BN * NODES;
    short* WtHi  = (short*)(dstv + BN * NODES);
    short* WtLo  = WtHi + FDIM * FDIM;
    short* WhTHi = WtLo + FDIM * FDIM;
    short* WhTLo = WhTHi + (size_t)BN * FDIM * NODES;

    detect_kernel<<<1, 256, 0, stream>>>((const unsigned short*)h, flag);
    prep_w_kernel<<<dim3(16, 16), 256, 0, stream>>>(W, flag, WtHi, WtLo);
    wh_mfma_kernel<<<dim3(8, BN), 256, 0, stream>>>(h, WtHi, WtLo, a, flag,
                                                    WhTHi, WhTLo, srcv, dstv);
    attn_mfma_kernel<<<dim3(16, BN), 256, 0, stream>>>(WhTHi, WhTLo, srcv, dstv,
                                                       adj, flag, d_out);
}

// Round 2
// 227.267 us; speedup vs baseline: 1.8893x; 1.2074x over previous
//
#include <hip/hip_runtime.h>
#include <hip/hip_bf16.h>

// GAT layer: B=8, N=8 (BN=64 batches), Nodes=512, IF=OF=256.
// MFMA on v_mfma_f32_16x16x32_bf16 with split-bf16 (hi+lo) operands.
//
// Pipeline:
//  K0: detect dtype -> flag in ws
//  KP: W -> Wt[f][k] bf16 hi/lo (transposed for B-fragments)
//  KA: Wh = h@W. 1024 blocks (BM=32), waves split over columns (4 ct each),
//      3-term split in fp32 mode. Writes WhT[bn][f][i] hi/lo; src/dst via
//      in-wave shuffle + cross-wave LDS reduction.
//  KB: softmax (P stored bf16-hi only) + out = elu((P@Wh)/rowsum),
//      2-term split (Ph*Whi + Ph*Wlo). XCD-swizzled block order.

#define ALPHA 0.2f
#define MASK_VAL -9000000000000000.0f
#define NODES 512
#define FDIM 256
#define BN 64

typedef float  f32x4 __attribute__((ext_vector_type(4)));
typedef int    i32x4 __attribute__((ext_vector_type(4)));
typedef short  s16x8 __attribute__((ext_vector_type(8)));
typedef short  s16x4 __attribute__((ext_vector_type(4)));
typedef unsigned int u32x4 __attribute__((ext_vector_type(4)));
typedef __bf16 bf16x8 __attribute__((ext_vector_type(8)));

__device__ __forceinline__ unsigned short f2bfu(float x) {
    __hip_bfloat16 b = __float2bfloat16(x);   // RNE
    unsigned short u; __builtin_memcpy(&u, &b, 2); return u;
}
__device__ __forceinline__ float bfu2f(unsigned short u) {
    unsigned int w = ((unsigned int)u) << 16; return __uint_as_float(w);
}

__device__ __forceinline__ f32x4 mfma16(s16x8 a, s16x8 b, f32x4 c) {
    return __builtin_amdgcn_mfma_f32_16x16x32_bf16(
        __builtin_bit_cast(bf16x8, a), __builtin_bit_cast(bf16x8, b), c, 0, 0, 0);
}

// Truncation-based hi/lo split of 8 fp32 -> 2x s16x8, packed via v_perm.
// hi = trunc-to-bf16 (exact bits), lo = trunc-to-bf16(x - hi). Residual ~2^-16.
__device__ __forceinline__ void split8(const float* __restrict__ p,
                                       s16x8& hi, s16x8& lo)
{
    f32x4 v0 = *(const f32x4*)p;
    f32x4 v1 = *(const f32x4*)(p + 4);
    float x[8] = {v0[0], v0[1], v0[2], v0[3], v1[0], v1[1], v1[2], v1[3]};
    u32x4 h, lw;
    #pragma unroll
    for (int d = 0; d < 4; ++d) {
        const unsigned u0 = __float_as_uint(x[2*d]);
        const unsigned u1 = __float_as_uint(x[2*d + 1]);
        h[d] = __builtin_amdgcn_perm(u1, u0, 0x07060302);   // {u1.hi16, u0.hi16}
        const float l0 = x[2*d]     - __uint_as_float(u0 & 0xFFFF0000u);
        const float l1 = x[2*d + 1] - __uint_as_float(u1 & 0xFFFF0000u);
        lw[d] = __builtin_amdgcn_perm(__float_as_uint(l1), __float_as_uint(l0),
                                      0x07060302);
    }
    hi = __builtin_bit_cast(s16x8, h);
    lo = __builtin_bit_cast(s16x8, lw);
}

// ---------------- K0: dtype detect ----------------
__global__ __launch_bounds__(256) void detect_kernel(const unsigned short* __restrict__ hraw,
                                                     int* __restrict__ flag)
{
    const int tid = threadIdx.x;
    float m = 0.0f;
    for (int i = tid; i < 16384; i += 256) {
        unsigned int w = ((unsigned int)hraw[i]) << 16;
        float v = __uint_as_float(w);
        v = fabsf(v);
        if (!(v == v)) v = 1e30f;
        m = fmaxf(m, v);
    }
    #pragma unroll
    for (int off = 32; off >= 1; off >>= 1)
        m = fmaxf(m, __shfl_down(m, off));
    __shared__ float red[4];
    if ((tid & 63) == 0) red[tid >> 6] = m;
    __syncthreads();
    if (tid == 0) {
        float mm = fmaxf(fmaxf(red[0], red[1]), fmaxf(red[2], red[3]));
        *flag = (mm > 1e4f) ? 1 : 0;
    }
}

// ---------------- KP: W -> Wt[f][k] bf16 hi/lo ----------------
__global__ __launch_bounds__(256) void prep_w_kernel(
    const void* __restrict__ Wv, const int* __restrict__ flagp,
    short* __restrict__ WtHi, short* __restrict__ WtLo)
{
    const int flag = *flagp;
    __shared__ float tile[16][17];
    const int tx = threadIdx.x & 15, ty = threadIdx.x >> 4;
    const int kk = blockIdx.y * 16 + ty;
    const int f  = blockIdx.x * 16 + tx;
    float v;
    if (flag) v = ((const float*)Wv)[kk * FDIM + f];
    else      v = bfu2f(((const unsigned short*)Wv)[kk * FDIM + f]);
    tile[ty][tx] = v;
    __syncthreads();
    const float x = tile[tx][ty];
    const int fo = blockIdx.x * 16 + ty;
    const int ko = blockIdx.y * 16 + tx;
    unsigned short h = f2bfu(x);
    WtHi[fo * FDIM + ko] = (short)h;
    WtLo[fo * FDIM + ko] = (short)f2bfu(x - bfu2f(h));  // exact 0 in bf16 mode
}

// ---------------- KA: Wh = h@W (MFMA) + src/dst ----------------
// grid (16, 64) = 1024 blocks, 256 thr = 4 waves. Block: 32 rows x 256 cols.
// Wave w -> col-tiles w*4..w*4+4 (64 cols), both 16-row strips.
// acc[2][4] (32 VGPR); per iter: 4 A-loads + 8 B-loads + 24 MFMA (fp32 mode).
__global__ __launch_bounds__(256) void wh_mfma_kernel(
    const void* __restrict__ hv,
    const short* __restrict__ WtHi, const short* __restrict__ WtLo,
    const void* __restrict__ av,
    const int* __restrict__ flagp,
    short* __restrict__ WhTHi, short* __restrict__ WhTLo,
    float* __restrict__ srcv, float* __restrict__ dstv)
{
    const int flag = *flagp;
    const int bn  = blockIdx.y;
    const int i0  = blockIdx.x * 32;
    const int tid = threadIdx.x;
    const int w   = tid >> 6;
    const int l   = tid & 63;
    const int fb  = l & 15;
    const int kg  = (l >> 4) * 8;

    __shared__ float red1[4][32];
    __shared__ float red2[4][32];

    f32x4 acc[2][4];
    #pragma unroll
    for (int rt = 0; rt < 2; ++rt)
        #pragma unroll
        for (int c = 0; c < 4; ++c) acc[rt][c] = f32x4{0.f, 0.f, 0.f, 0.f};

    const size_t hb0 = ((size_t)bn * NODES + i0 + fb) * FDIM;  // strip 0, A-row fb
    const size_t hb1 = hb0 + (size_t)16 * FDIM;                // strip 1

    if (flag) {
        for (int k0 = 0; k0 < FDIM; k0 += 32) {
            const int kk = k0 + kg;
            s16x8 ah0, al0, ah1, al1;
            split8((const float*)hv + hb0 + kk, ah0, al0);
            split8((const float*)hv + hb1 + kk, ah1, al1);
            #pragma unroll
            for (int c = 0; c < 4; ++c) {
                const int f = (w * 4 + c) * 16 + fb;
                const s16x8 bh = *(const s16x8*)(WtHi + f * FDIM + kk);
                const s16x8 bl = *(const s16x8*)(WtLo + f * FDIM + kk);
                acc[0][c] = mfma16(ah0, bh, acc[0][c]);
                acc[0][c] = mfma16(al0, bh, acc[0][c]);
                acc[0][c] = mfma16(ah0, bl, acc[0][c]);
                acc[1][c] = mfma16(ah1, bh, acc[1][c]);
                acc[1][c] = mfma16(al1, bh, acc[1][c]);
                acc[1][c] = mfma16(ah1, bl, acc[1][c]);
            }
        }
    } else {
        for (int k0 = 0; k0 < FDIM; k0 += 32) {
            const int kk = k0 + kg;
            const s16x8 ah0 = *(const s16x8*)((const short*)hv + hb0 + kk);
            const s16x8 ah1 = *(const s16x8*)((const short*)hv + hb1 + kk);
            #pragma unroll
            for (int c = 0; c < 4; ++c) {
                const int f = (w * 4 + c) * 16 + fb;
                const s16x8 bh = *(const s16x8*)(WtHi + f * FDIM + kk);
                acc[0][c] = mfma16(ah0, bh, acc[0][c]);   // inputs exact in bf16 mode
                acc[1][c] = mfma16(ah1, bh, acc[1][c]);
            }
        }
    }

    // Write WhT[bn][f][i] hi/lo.  D layout: row = (l>>4)*4 + r, col = f.
    const int r0 = (l >> 4) * 4;
    const size_t wbase = (size_t)bn * FDIM * NODES;
    #pragma unroll
    for (int rt = 0; rt < 2; ++rt) {
        const int orow = i0 + rt * 16 + r0;
        #pragma unroll
        for (int c = 0; c < 4; ++c) {
            const int f = (w * 4 + c) * 16 + fb;
            s16x4 hi4, lo4;
            #pragma unroll
            for (int r = 0; r < 4; ++r) {
                float x = acc[rt][c][r];
                unsigned short h = f2bfu(x);
                hi4[r] = (short)h;
                lo4[r] = (short)f2bfu(x - bfu2f(h));
            }
            *(s16x4*)(WhTHi + wbase + (size_t)f * NODES + orow) = hi4;
            *(s16x4*)(WhTLo + wbase + (size_t)f * NODES + orow) = lo4;
        }
    }

    // src/dst: in-wave partial (4 ct), then cross-wave LDS reduction.
    float a1v[4], a2v[4];
    #pragma unroll
    for (int c = 0; c < 4; ++c) {
        const int f = (w * 4 + c) * 16 + fb;
        if (flag) {
            a1v[c] = ((const float*)av)[f];
            a2v[c] = ((const float*)av)[FDIM + f];
        } else {
            a1v[c] = bfu2f(((const unsigned short*)av)[f]);
            a2v[c] = bfu2f(((const unsigned short*)av)[FDIM + f]);
        }
    }
    #pragma unroll
    for (int rt = 0; rt < 2; ++rt) {
        #pragma unroll
        for (int r = 0; r < 4; ++r) {
            float s1 = 0.f, s2 = 0.f;
            #pragma unroll
            for (int c = 0; c < 4; ++c) {
                s1 = fmaf(acc[rt][c][r], a1v[c], s1);
                s2 = fmaf(acc[rt][c][r], a2v[c], s2);
            }
            #pragma unroll
            for (int off = 1; off <= 8; off <<= 1) {
                s1 += __shfl_xor(s1, off);
                s2 += __shfl_xor(s2, off);
            }
            if (fb == 0) {
                red1[w][rt * 16 + r0 + r] = s1;
                red2[w][rt * 16 + r0 + r] = s2;
            }
        }
    }
    __syncthreads();
    if (tid < 32) {
        float s1 = red1[0][tid] + red1[1][tid] + red1[2][tid] + red1[3][tid];
        float s2 = red2[0][tid] + red2[1][tid] + red2[2][tid] + red2[3][tid];
        srcv[bn * NODES + i0 + tid] = s1;
        dstv[bn * NODES + i0 + tid] = s2;
    }
}

// ---------------- KB: softmax + att@Wh (MFMA) + elu ----------------
// 1024 blocks (XCD-swizzled), 256 thr = 4 waves. Block: 32 att rows, K=512.
// Softmax: wave w owns rows w*8..w*8+8; 8 lanes/row. P -> LDS bf16 hi only.
// MFMA: wave w -> col-tiles w*4..w*4+4, 2 row-tiles, 2-term (Ph*Whi + Ph*Wlo).
__global__ __launch_bounds__(256) void attn_mfma_kernel(
    const short* __restrict__ WhTHi, const short* __restrict__ WhTLo,
    const float* __restrict__ srcv, const float* __restrict__ dstv,
    const int* __restrict__ adj, const int* __restrict__ flagp,
    void* __restrict__ out)
{
    const int flag = *flagp;
    const int bid = blockIdx.x;
    const int sw  = (bid & 7) * 128 + (bid >> 3);   // bijective: 1024 % 8 == 0
    const int bn  = sw >> 4;                         // 16 consecutive sw share bn
    const int i0  = (sw & 15) * 32;
    const int tid = threadIdx.x;
    const int w   = tid >> 6;
    const int l   = tid & 63;

    __shared__ short aHi[32][520];     // pad 8 shorts: 1040 B row stride
    __shared__ float rowinv[32];

    const int lr = w * 8 + (l >> 3);
    const int jc = (l & 7) * 64;
    const float srow = srcv[bn * NODES + i0 + lr];
    const int*   adjrow = adj + (size_t)(i0 + lr) * NODES;
    const float* drow   = dstv + bn * NODES;

    // pass 1: row max (includes MASK_VAL like reference)
    float m = -3.0e38f;
    #pragma unroll
    for (int g = 0; g < 8; ++g) {
        const int j = jc + g * 8;
        const i32x4 q0 = *(const i32x4*)(adjrow + j);
        const i32x4 q1 = *(const i32x4*)(adjrow + j + 4);
        const f32x4 d0 = *(const f32x4*)(drow + j);
        const f32x4 d1 = *(const f32x4*)(drow + j + 4);
        #pragma unroll
        for (int e = 0; e < 4; ++e) {
            float ev = srow + d0[e];
            ev = (ev > 0.f) ? ev : ALPHA * ev;
            m = fmaxf(m, (q0[e] > 0) ? ev : MASK_VAL);
            float ew = srow + d1[e];
            ew = (ew > 0.f) ? ew : ALPHA * ew;
            m = fmaxf(m, (q1[e] > 0) ? ew : MASK_VAL);
        }
    }
    #pragma unroll
    for (int off = 1; off <= 4; off <<= 1) m = fmaxf(m, __shfl_xor(m, off));

    // pass 2: exp, sum, store P (hi only) to LDS
    float s = 0.f;
    #pragma unroll
    for (int g = 0; g < 8; ++g) {
        const int j = jc + g * 8;
        const i32x4 q0 = *(const i32x4*)(adjrow + j);
        const i32x4 q1 = *(const i32x4*)(adjrow + j + 4);
        const f32x4 d0 = *(const f32x4*)(drow + j);
        const f32x4 d1 = *(const f32x4*)(drow + j + 4);
        s16x8 ph;
        #pragma unroll
        for (int e = 0; e < 4; ++e) {
            float ev = srow + d0[e];
            ev = (ev > 0.f) ? ev : ALPHA * ev;
            ev = (q0[e] > 0) ? ev : MASK_VAL;
            float p = __expf(ev - m);      // masked -> 0; all-masked row -> 1
            s += p;
            ph[e] = (short)f2bfu(p);
            float ew = srow + d1[e];
            ew = (ew > 0.f) ? ew : ALPHA * ew;
            ew = (q1[e] > 0) ? ew : MASK_VAL;
            float p2 = __expf(ew - m);
            s += p2;
            ph[4 + e] = (short)f2bfu(p2);
        }
        *(s16x8*)&aHi[lr][j] = ph;
    }
    #pragma unroll
    for (int off = 1; off <= 4; off <<= 1) s += __shfl_xor(s, off);
    if ((l & 7) == 0) rowinv[lr] = 1.0f / s;
    __syncthreads();

    // MFMA phase
    const int fb  = l & 15;
    const int kg  = (l >> 4) * 8;
    const int wct = w * 4;
    const size_t wbase = (size_t)bn * FDIM * NODES;

    f32x4 acc[2][4];
    #pragma unroll
    for (int rt = 0; rt < 2; ++rt)
        #pragma unroll
        for (int c = 0; c < 4; ++c) acc[rt][c] = f32x4{0.f, 0.f, 0.f, 0.f};

    for (int k0 = 0; k0 < NODES; k0 += 32) {
        const int kk = k0 + kg;
        const s16x8 a0 = *(const s16x8*)&aHi[fb][kk];
        const s16x8 a1 = *(const s16x8*)&aHi[16 + fb][kk];
        #pragma unroll
        for (int c = 0; c < 4; ++c) {
            const int f = (wct + c) * 16 + fb;
            const s16x8 bh = *(const s16x8*)(WhTHi + wbase + (size_t)f * NODES + kk);
            const s16x8 bl = *(const s16x8*)(WhTLo + wbase + (size_t)f * NODES + kk);
            acc[0][c] = mfma16(a0, bh, acc[0][c]);
            acc[0][c] = mfma16(a0, bl, acc[0][c]);
            acc[1][c] = mfma16(a1, bh, acc[1][c]);
            acc[1][c] = mfma16(a1, bl, acc[1][c]);
        }
    }

    // epilogue: scale by 1/rowsum, elu, store
    const int r0 = (l >> 4) * 4;
    #pragma unroll
    for (int rt = 0; rt < 2; ++rt) {
        float inv[4];
        #pragma unroll
        for (int r = 0; r < 4; ++r) inv[r] = rowinv[rt * 16 + r0 + r];
        #pragma unroll
        for (int c = 0; c < 4; ++c) {
            const int f = (wct + c) * 16 + fb;
            #pragma unroll
            for (int r = 0; r < 4; ++r) {
                float v = acc[rt][c][r] * inv[r];
                v = (v > 0.f) ? v : expm1f(v);
                const size_t o = ((size_t)bn * NODES + i0 + rt * 16 + r0 + r) * FDIM + f;
                if (flag) ((float*)out)[o] = v;
                else      ((unsigned short*)out)[o] = f2bfu(v);
            }
        }
    }
}

extern "C" void kernel_launch(void* const* d_in, const int* in_sizes, int n_in,
                              void* d_out, int out_size, void* d_ws, size_t ws_size,
                              hipStream_t stream)
{
    const void* h   = d_in[0];
    const int*  adj = (const int*)d_in[1];
    const void* W   = d_in[2];
    const void* a   = d_in[3];

    // ws layout:
    //  [0..255]      flag (+pad)
    //  src  fp32     BN*NODES          = 128 KB
    //  dst  fp32     BN*NODES          = 128 KB
    //  WtHi bf16     FDIM*FDIM         = 128 KB
    //  WtLo bf16     FDIM*FDIM         = 128 KB
    //  WhTHi bf16    BN*FDIM*NODES     = 16.78 MB
    //  WhTLo bf16    BN*FDIM*NODES     = 16.78 MB
    int*   flag  = (int*)d_ws;
    float* srcv  = (float*)d_ws + 64;
    float* dstv  = srcv + BN * NODES;
    short* WtHi  = (short*)(dstv + BN * NODES);
    short* WtLo  = WtHi + FDIM * FDIM;
    short* WhTHi = WtLo + FDIM * FDIM;
    short* WhTLo = WhTHi + (size_t)BN * FDIM * NODES;

    detect_kernel<<<1, 256, 0, stream>>>((const unsigned short*)h, flag);
    prep_w_kernel<<<dim3(16, 16), 256, 0, stream>>>(W, flag, WtHi, WtLo);
    wh_mfma_kernel<<<dim3(16, BN), 256, 0, stream>>>(h, WtHi, WtLo, a, flag,
                                                     WhTHi, WhTLo, srcv, dstv);
    attn_mfma_kernel<<<1024, 256, 0, stream>>>(WhTHi, WhTLo, srcv, dstv,
                                               adj, flag, d_out);
}

// Round 3
// 217.618 us; speedup vs baseline: 1.9731x; 1.0443x over previous
//
#include <hip/hip_runtime.h>
#include <hip/hip_bf16.h>

// GAT layer: B=8, N=8 (BN=64 batches), Nodes=512, IF=OF=256.
// MFMA on v_mfma_f32_16x16x32_bf16 with split-bf16 (hi+lo) operands.
//
// Pipeline:
//  K0: detect dtype -> flag in ws
//  KP: W -> Wt[f][k] bf16 hi/lo (transposed for B-fragments)
//  KA: Wh = h@W. B(Wt) staged via wave-private global_load_lds double-buffer,
//      counted vmcnt, no in-loop barriers. A(h) prefetched 1 step ahead.
//  KB: coalesced wave-per-row softmax -> P in swizzled LDS; PV GEMM with
//      B(WhT) staged via wave-private 3-deep global_load_lds pipeline.

#define ALPHA 0.2f
#define MASK_VAL -9000000000000000.0f
#define NODES 512
#define FDIM 256
#define BN 64

typedef float  f32x4 __attribute__((ext_vector_type(4)));
typedef int    i32x4 __attribute__((ext_vector_type(4)));
typedef short  s16x8 __attribute__((ext_vector_type(8)));
typedef short  s16x4 __attribute__((ext_vector_type(4)));
typedef __bf16 bf16x8 __attribute__((ext_vector_type(8)));

__device__ __forceinline__ unsigned short f2bfu(float x) {
    __hip_bfloat16 b = __float2bfloat16(x);   // RNE
    unsigned short u; __builtin_memcpy(&u, &b, 2); return u;
}
__device__ __forceinline__ float bfu2f(unsigned short u) {
    unsigned int w = ((unsigned int)u) << 16; return __uint_as_float(w);
}

__device__ __forceinline__ f32x4 mfma16(s16x8 a, s16x8 b, f32x4 c) {
    return __builtin_amdgcn_mfma_f32_16x16x32_bf16(
        __builtin_bit_cast(bf16x8, a), __builtin_bit_cast(bf16x8, b), c, 0, 0, 0);
}

// hi/lo split of 8 fp32 values (truncation split; residual ~2^-16 rel).
__device__ __forceinline__ void split8v(f32x4 v0, f32x4 v1, s16x8& hi, s16x8& lo)
{
    float x[8] = {v0[0], v0[1], v0[2], v0[3], v1[0], v1[1], v1[2], v1[3]};
    unsigned hw[4], lw[4];
    #pragma unroll
    for (int d = 0; d < 4; ++d) {
        const unsigned u0 = __float_as_uint(x[2*d]);
        const unsigned u1 = __float_as_uint(x[2*d + 1]);
        hw[d] = __builtin_amdgcn_perm(u1, u0, 0x07060302);
        const float l0 = x[2*d]     - __uint_as_float(u0 & 0xFFFF0000u);
        const float l1 = x[2*d + 1] - __uint_as_float(u1 & 0xFFFF0000u);
        lw[d] = __builtin_amdgcn_perm(__float_as_uint(l1), __float_as_uint(l0),
                                      0x07060302);
    }
    hi = __builtin_bit_cast(s16x8, *(unsigned(*)[4])hw);
    lo = __builtin_bit_cast(s16x8, *(unsigned(*)[4])lw);
}

// ---- async global->LDS helpers -------------------------------------------
__device__ __forceinline__ void gll16(const void* g, void* l) {
    __builtin_amdgcn_global_load_lds(
        (const __attribute__((address_space(1))) unsigned int*)g,
        (__attribute__((address_space(3))) unsigned int*)l,
        16, 0, 0);
}
__device__ __forceinline__ unsigned lds_off(const void* p) {
    return (unsigned)(unsigned long long)
        (const __attribute__((address_space(3))) void*)p;
}
__device__ __forceinline__ s16x8 ds_read_b128s(unsigned off) {
    s16x8 r;
    asm volatile("ds_read_b128 %0, %1" : "=v"(r) : "v"(off));
    return r;
}

// Stage one wave-private [64 f][32 k] slice (hi+lo) = 8 x 1KB global_load_lds.
// LDS layout: hi at +0 (4KB), lo at +4096; row = 64B, chunk-XOR-swizzled:
// data chunk (cq^s) stored at slot cq, s = (f_local>>1)&3.  Read side XORs back.
__device__ __forceinline__ void stage_slice8(const short* __restrict__ ghi,
                                             const short* __restrict__ glo,
                                             int f0, int k0, int rowElems,
                                             char* dst, int l)
{
    const int fl = l >> 2;     // 0..15
    const int cq = l & 3;
    #pragma unroll
    for (int i = 0; i < 4; ++i) {
        const int flo = i*16 + fl;
        const int kb  = ((cq ^ ((flo >> 1) & 3)) << 4);
        gll16((const char*)(ghi + (size_t)(f0 + flo) * rowElems + k0) + kb,
              dst + i*1024);
    }
    #pragma unroll
    for (int i = 0; i < 4; ++i) {
        const int flo = i*16 + fl;
        const int kb  = ((cq ^ ((flo >> 1) & 3)) << 4);
        gll16((const char*)(glo + (size_t)(f0 + flo) * rowElems + k0) + kb,
              dst + 4096 + i*1024);
    }
}
// hi-only variant (bf16 mode: Wt lo is exactly zero)
__device__ __forceinline__ void stage_slice4(const short* __restrict__ ghi,
                                             int f0, int k0, int rowElems,
                                             char* dst, int l)
{
    const int fl = l >> 2;
    const int cq = l & 3;
    #pragma unroll
    for (int i = 0; i < 4; ++i) {
        const int flo = i*16 + fl;
        const int kb  = ((cq ^ ((flo >> 1) & 3)) << 4);
        gll16((const char*)(ghi + (size_t)(f0 + flo) * rowElems + k0) + kb,
              dst + i*1024);
    }
}

// ---------------- K0: dtype detect ----------------
__global__ __launch_bounds__(256) void detect_kernel(const unsigned short* __restrict__ hraw,
                                                     int* __restrict__ flag)
{
    const int tid = threadIdx.x;
    float m = 0.0f;
    for (int i = tid; i < 16384; i += 256) {
        unsigned int w = ((unsigned int)hraw[i]) << 16;
        float v = __uint_as_float(w);
        v = fabsf(v);
        if (!(v == v)) v = 1e30f;
        m = fmaxf(m, v);
    }
    #pragma unroll
    for (int off = 32; off >= 1; off >>= 1)
        m = fmaxf(m, __shfl_down(m, off));
    __shared__ float red[4];
    if ((tid & 63) == 0) red[tid >> 6] = m;
    __syncthreads();
    if (tid == 0) {
        float mm = fmaxf(fmaxf(red[0], red[1]), fmaxf(red[2], red[3]));
        *flag = (mm > 1e4f) ? 1 : 0;
    }
}

// ---------------- KP: W -> Wt[f][k] bf16 hi/lo ----------------
__global__ __launch_bounds__(256) void prep_w_kernel(
    const void* __restrict__ Wv, const int* __restrict__ flagp,
    short* __restrict__ WtHi, short* __restrict__ WtLo)
{
    const int flag = *flagp;
    __shared__ float tile[16][17];
    const int tx = threadIdx.x & 15, ty = threadIdx.x >> 4;
    const int kk = blockIdx.y * 16 + ty;
    const int f  = blockIdx.x * 16 + tx;
    float v;
    if (flag) v = ((const float*)Wv)[kk * FDIM + f];
    else      v = bfu2f(((const unsigned short*)Wv)[kk * FDIM + f]);
    tile[ty][tx] = v;
    __syncthreads();
    const float x = tile[tx][ty];
    const int fo = blockIdx.x * 16 + ty;
    const int ko = blockIdx.y * 16 + tx;
    unsigned short h = f2bfu(x);
    WtHi[fo * FDIM + ko] = (short)h;
    WtLo[fo * FDIM + ko] = (short)f2bfu(x - bfu2f(h));  // exact 0 in bf16 mode
}

// ---------------- KA: Wh = h@W (MFMA, staged B, prefetched A) -------------
// grid (16, 64), 256 thr = 4 waves; block: 32 rows x 256 cols, K=256.
// Wave w owns f-slice w*64..w*64+64: stages its own B (Wt) slices; reads
// are wave-private so the K-loop has NO barriers, only counted vmcnt.
__global__ __launch_bounds__(256, 2) void wh_mfma_kernel(
    const void* __restrict__ hv,
    const short* __restrict__ WtHi, const short* __restrict__ WtLo,
    const void* __restrict__ av,
    const int* __restrict__ flagp,
    short* __restrict__ WhTHi, short* __restrict__ WhTLo,
    float* __restrict__ srcv, float* __restrict__ dstv)
{
    __shared__ char  Bb[2][4][8192];   // 64KB: 2 bufs x 4 waves x (hi4K+lo4K)
    __shared__ float red1[4][32];
    __shared__ float red2[4][32];

    const int flag = *flagp;
    const int bn  = blockIdx.y;
    const int i0  = blockIdx.x * 32;
    const int tid = threadIdx.x;
    const int w   = tid >> 6;
    const int l   = tid & 63;
    const int fb  = l & 15;
    const int cqr = l >> 4;
    const int f0  = w * 64;

    char* smemB = (char*)&Bb[0][0][0];
    const unsigned bb = lds_off(smemB) + (unsigned)(w * 8192);

    unsigned boffH[4];
    #pragma unroll
    for (int c = 0; c < 4; ++c) {
        const int flo = c*16 + fb;
        boffH[c] = (unsigned)(flo*64 + ((cqr ^ ((flo >> 1) & 3)) << 4));
    }

    f32x4 acc[2][4];
    #pragma unroll
    for (int rt = 0; rt < 2; ++rt)
        #pragma unroll
        for (int c = 0; c < 4; ++c) acc[rt][c] = f32x4{0.f, 0.f, 0.f, 0.f};

    const size_t hb0 = ((size_t)bn * NODES + i0 + fb) * FDIM;
    const size_t hb1 = hb0 + (size_t)16 * FDIM;

    if (flag) {
        // -------- fp32 mode: 3-term split, stage hi+lo --------
        const float* hf = (const float*)hv;
        const int kk0 = cqr * 8;
        f32x4 c00 = *(const f32x4*)(hf + hb0 + kk0);
        f32x4 c01 = *(const f32x4*)(hf + hb0 + kk0 + 4);
        f32x4 c10 = *(const f32x4*)(hf + hb1 + kk0);
        f32x4 c11 = *(const f32x4*)(hf + hb1 + kk0 + 4);
        stage_slice8(WtHi, WtLo, f0, 0, FDIM, smemB + w*8192, l);
        #pragma unroll
        for (int t = 0; t < 8; ++t) {
            const int kn = ((t+1) & 7) * 32 + cqr * 8;
            f32x4 n00 = *(const f32x4*)(hf + hb0 + kn);
            f32x4 n01 = *(const f32x4*)(hf + hb0 + kn + 4);
            f32x4 n10 = *(const f32x4*)(hf + hb1 + kn);
            f32x4 n11 = *(const f32x4*)(hf + hb1 + kn + 4);
            stage_slice8(WtHi, WtLo, f0, ((t+1) & 7) * 32, FDIM,
                         smemB + ((t+1) & 1) * 32768 + w*8192, l);
            asm volatile("s_waitcnt vmcnt(12)" ::: "memory");
            const unsigned sb = bb + (unsigned)((t & 1) * 32768);
            s16x8 b[8];
            #pragma unroll
            for (int c = 0; c < 4; ++c) {
                b[c]   = ds_read_b128s(sb + boffH[c]);
                b[4+c] = ds_read_b128s(sb + boffH[c] + 4096);
            }
            asm volatile("s_waitcnt lgkmcnt(0)" ::: "memory");
            __builtin_amdgcn_sched_barrier(0);
            s16x8 ah0, al0, ah1, al1;
            split8v(c00, c01, ah0, al0);
            split8v(c10, c11, ah1, al1);
            #pragma unroll
            for (int c = 0; c < 4; ++c) {
                acc[0][c] = mfma16(ah0, b[c],   acc[0][c]);
                acc[0][c] = mfma16(al0, b[c],   acc[0][c]);
                acc[0][c] = mfma16(ah0, b[4+c], acc[0][c]);
                acc[1][c] = mfma16(ah1, b[c],   acc[1][c]);
                acc[1][c] = mfma16(al1, b[c],   acc[1][c]);
                acc[1][c] = mfma16(ah1, b[4+c], acc[1][c]);
            }
            c00 = n00; c01 = n01; c10 = n10; c11 = n11;
        }
    } else {
        // -------- bf16 mode: exact inputs, hi-only --------
        const short* hs = (const short*)hv;
        const int kk0 = cqr * 8;
        s16x8 c0 = *(const s16x8*)(hs + hb0 + kk0);
        s16x8 c1 = *(const s16x8*)(hs + hb1 + kk0);
        stage_slice4(WtHi, f0, 0, FDIM, smemB + w*8192, l);
        #pragma unroll
        for (int t = 0; t < 8; ++t) {
            const int kn = ((t+1) & 7) * 32 + cqr * 8;
            s16x8 n0 = *(const s16x8*)(hs + hb0 + kn);
            s16x8 n1 = *(const s16x8*)(hs + hb1 + kn);
            stage_slice4(WtHi, f0, ((t+1) & 7) * 32, FDIM,
                         smemB + ((t+1) & 1) * 32768 + w*8192, l);
            asm volatile("s_waitcnt vmcnt(6)" ::: "memory");
            const unsigned sb = bb + (unsigned)((t & 1) * 32768);
            s16x8 b[4];
            #pragma unroll
            for (int c = 0; c < 4; ++c) b[c] = ds_read_b128s(sb + boffH[c]);
            asm volatile("s_waitcnt lgkmcnt(0)" ::: "memory");
            __builtin_amdgcn_sched_barrier(0);
            #pragma unroll
            for (int c = 0; c < 4; ++c) {
                acc[0][c] = mfma16(c0, b[c], acc[0][c]);
                acc[1][c] = mfma16(c1, b[c], acc[1][c]);
            }
            c0 = n0; c1 = n1;
        }
    }

    // Write WhT[bn][f][i] hi/lo.  D layout: row = (l>>4)*4 + r, col = f.
    const int r0 = cqr * 4;
    const size_t wbase = (size_t)bn * FDIM * NODES;
    #pragma unroll
    for (int rt = 0; rt < 2; ++rt) {
        const int orow = i0 + rt * 16 + r0;
        #pragma unroll
        for (int c = 0; c < 4; ++c) {
            const int f = f0 + c * 16 + fb;
            s16x4 hi4, lo4;
            #pragma unroll
            for (int r = 0; r < 4; ++r) {
                float x = acc[rt][c][r];
                unsigned short h = f2bfu(x);
                hi4[r] = (short)h;
                lo4[r] = (short)f2bfu(x - bfu2f(h));
            }
            *(s16x4*)(WhTHi + wbase + (size_t)f * NODES + orow) = hi4;
            *(s16x4*)(WhTLo + wbase + (size_t)f * NODES + orow) = lo4;
        }
    }

    // src/dst: in-wave partial (4 ct), then cross-wave LDS reduction.
    float a1v[4], a2v[4];
    #pragma unroll
    for (int c = 0; c < 4; ++c) {
        const int f = f0 + c * 16 + fb;
        if (flag) {
            a1v[c] = ((const float*)av)[f];
            a2v[c] = ((const float*)av)[FDIM + f];
        } else {
            a1v[c] = bfu2f(((const unsigned short*)av)[f]);
            a2v[c] = bfu2f(((const unsigned short*)av)[FDIM + f]);
        }
    }
    #pragma unroll
    for (int rt = 0; rt < 2; ++rt) {
        #pragma unroll
        for (int r = 0; r < 4; ++r) {
            float s1 = 0.f, s2 = 0.f;
            #pragma unroll
            for (int c = 0; c < 4; ++c) {
                s1 = fmaf(acc[rt][c][r], a1v[c], s1);
                s2 = fmaf(acc[rt][c][r], a2v[c], s2);
            }
            #pragma unroll
            for (int off = 1; off <= 8; off <<= 1) {
                s1 += __shfl_xor(s1, off);
                s2 += __shfl_xor(s2, off);
            }
            if (fb == 0) {
                red1[w][rt * 16 + r0 + r] = s1;
                red2[w][rt * 16 + r0 + r] = s2;
            }
        }
    }
    __syncthreads();
    if (tid < 32) {
        float s1 = red1[0][tid] + red1[1][tid] + red1[2][tid] + red1[3][tid];
        float s2 = red2[0][tid] + red2[1][tid] + red2[2][tid] + red2[3][tid];
        srcv[bn * NODES + i0 + tid] = s1;
        dstv[bn * NODES + i0 + tid] = s2;
    }
}

// ---------------- KB: softmax + att@Wh (staged MFMA) + elu ----------------
// 1024 blocks (XCD-swizzled), 256 thr = 4 waves; block: 32 rows, K=512.
// Softmax: wave w owns rows w*8..w*8+8, one row at a time, lane l covers
// j=8l..8l+8 (coalesced 1KB loads). P -> LDS bf16 (chunk-XOR swizzled).
// PV: wave-private 3-deep staged B pipeline, counted vmcnt, no barriers.
__global__ __launch_bounds__(256, 1) void attn_mfma_kernel(
    const short* __restrict__ WhTHi, const short* __restrict__ WhTLo,
    const float* __restrict__ srcv, const float* __restrict__ dstv,
    const int* __restrict__ adj, const int* __restrict__ flagp,
    void* __restrict__ out)
{
    __shared__ short P[32][512];        // 32KB, swizzled
    __shared__ char  Bb[3][4][8192];    // 96KB: 3 bufs x 4 waves x (hi+lo)
    __shared__ float rowinv[32];

    const int flag = *flagp;
    const int bid = blockIdx.x;
    const int sw  = (bid & 7) * 128 + (bid >> 3);   // bijective: 1024 % 8 == 0
    const int bn  = sw >> 4;
    const int i0  = (sw & 15) * 32;
    const int tid = threadIdx.x;
    const int w   = tid >> 6;
    const int l   = tid & 63;
    const int fb  = l & 15;
    const int cqr = l >> 4;
    const int f0  = w * 64;

    const short* bhi = WhTHi + (size_t)bn * FDIM * NODES;
    const short* blo = WhTLo + (size_t)bn * FDIM * NODES;
    char* smemB = (char*)&Bb[0][0][0];
    const unsigned bb = lds_off(smemB) + (unsigned)(w * 8192);

    // prologue: stage slices 0,1 (they land while softmax runs)
    stage_slice8(bhi, blo, f0, 0,  NODES, smemB + 0*32768 + w*8192, l);
    stage_slice8(bhi, blo, f0, 32, NODES, smemB + 1*32768 + w*8192, l);

    // ---- softmax: wave per row, coalesced ----
    {
        const float* drow = dstv + bn * NODES;
        const int j = l * 8;
        #pragma unroll 2
        for (int rr = 0; rr < 8; ++rr) {
            const int r = w * 8 + rr;
            const int* adjrow = adj + (size_t)(i0 + r) * NODES;
            const float srow = srcv[bn * NODES + i0 + r];
            const i32x4 q0 = *(const i32x4*)(adjrow + j);
            const i32x4 q1 = *(const i32x4*)(adjrow + j + 4);
            const f32x4 d0 = *(const f32x4*)(drow + j);
            const f32x4 d1 = *(const f32x4*)(drow + j + 4);
            float e[8];
            #pragma unroll
            for (int k = 0; k < 4; ++k) {
                float ev = srow + d0[k];
                ev = (ev > 0.f) ? ev : ALPHA * ev;
                e[k] = (q0[k] > 0) ? ev : MASK_VAL;
                float ew = srow + d1[k];
                ew = (ew > 0.f) ? ew : ALPHA * ew;
                e[4+k] = (q1[k] > 0) ? ew : MASK_VAL;
            }
            float m = e[0];
            #pragma unroll
            for (int k = 1; k < 8; ++k) m = fmaxf(m, e[k]);
            #pragma unroll
            for (int off = 1; off <= 32; off <<= 1) m = fmaxf(m, __shfl_xor(m, off));
            float s = 0.f;
            s16x8 ph;
            #pragma unroll
            for (int k = 0; k < 8; ++k) {
                float p = __expf(e[k] - m);   // masked -> 0; all-masked row -> 1
                s += p;
                ph[k] = (short)f2bfu(p);
            }
            #pragma unroll
            for (int off = 1; off <= 32; off <<= 1) s += __shfl_xor(s, off);
            // swizzled P write: chunk l stored at chunk l ^ (r&7)
            const unsigned kb = ((unsigned)(l * 16)) ^ ((unsigned)((r & 7) << 4));
            *(s16x8*)((char*)&P[r][0] + kb) = ph;
            if (l == 0) rowinv[r] = 1.0f / s;
        }
    }
    __syncthreads();

    // ---- PV GEMM: 16 K-steps, 3-deep wave-private pipeline ----
    f32x4 acc[2][4];
    #pragma unroll
    for (int rt = 0; rt < 2; ++rt)
        #pragma unroll
        for (int c = 0; c < 4; ++c) acc[rt][c] = f32x4{0.f, 0.f, 0.f, 0.f};

    unsigned boffH[4];
    #pragma unroll
    for (int c = 0; c < 4; ++c) {
        const int flo = c*16 + fb;
        boffH[c] = (unsigned)(flo*64 + ((cqr ^ ((flo >> 1) & 3)) << 4));
    }
    const unsigned pbase = lds_off(&P[0][0]);
    const unsigned ar0 = pbase + (unsigned)(fb * 1024);
    const unsigned ar1 = pbase + (unsigned)((16 + fb) * 1024);
    const unsigned aswz = (unsigned)((fb & 7) << 4);   // (16+fb)&7 == fb&7

    int cur = 0;
    for (int t = 0; t < 16; ++t) {
        int nxt = cur + 2; if (nxt >= 3) nxt -= 3;
        stage_slice8(bhi, blo, f0, ((t + 2) & 15) * 32, NODES,
                     smemB + nxt * 32768 + w * 8192, l);
        asm volatile("s_waitcnt vmcnt(16)" ::: "memory");
        const unsigned sb = bb + (unsigned)(cur * 32768);
        s16x8 b[8];
        #pragma unroll
        for (int c = 0; c < 4; ++c) {
            b[c]   = ds_read_b128s(sb + boffH[c]);
            b[4+c] = ds_read_b128s(sb + boffH[c] + 4096);
        }
        const unsigned kbb = (unsigned)((t * 32 + cqr * 8) * 2);
        s16x8 a0 = ds_read_b128s(ar0 + (kbb ^ aswz));
        s16x8 a1 = ds_read_b128s(ar1 + (kbb ^ aswz));
        asm volatile("s_waitcnt lgkmcnt(0)" ::: "memory");
        __builtin_amdgcn_sched_barrier(0);
        #pragma unroll
        for (int c = 0; c < 4; ++c) {
            acc[0][c] = mfma16(a0, b[c],   acc[0][c]);
            acc[0][c] = mfma16(a0, b[4+c], acc[0][c]);
            acc[1][c] = mfma16(a1, b[c],   acc[1][c]);
            acc[1][c] = mfma16(a1, b[4+c], acc[1][c]);
        }
        cur = (cur + 1 == 3) ? 0 : cur + 1;
    }

    // epilogue: scale by 1/rowsum, elu, store
    const int r0 = cqr * 4;
    #pragma unroll
    for (int rt = 0; rt < 2; ++rt) {
        float inv[4];
        #pragma unroll
        for (int r = 0; r < 4; ++r) inv[r] = rowinv[rt * 16 + r0 + r];
        #pragma unroll
        for (int c = 0; c < 4; ++c) {
            const int f = f0 + c * 16 + fb;
            #pragma unroll
            for (int r = 0; r < 4; ++r) {
                float v = acc[rt][c][r] * inv[r];
                v = (v > 0.f) ? v : expm1f(v);
                const size_t o = ((size_t)bn * NODES + i0 + rt * 16 + r0 + r) * FDIM + f;
                if (flag) ((float*)out)[o] = v;
                else      ((unsigned short*)out)[o] = f2bfu(v);
            }
        }
    }
}

extern "C" void kernel_launch(void* const* d_in, const int* in_sizes, int n_in,
                              void* d_out, int out_size, void* d_ws, size_t ws_size,
                              hipStream_t stream)
{
    const void* h   = d_in[0];
    const int*  adj = (const int*)d_in[1];
    const void* W   = d_in[2];
    const void* a   = d_in[3];

    // ws layout:
    //  [0..255]      flag (+pad)
    //  src  fp32     BN*NODES          = 128 KB
    //  dst  fp32     BN*NODES          = 128 KB
    //  WtHi bf16     FDIM*FDIM         = 128 KB
    //  WtLo bf16     FDIM*FDIM         = 128 KB
    //  WhTHi bf16    BN*FDIM*NODES     = 16.78 MB
    //  WhTLo bf16    BN*FDIM*NODES     = 16.78 MB
    int*   flag  = (int*)d_ws;
    float* srcv  = (float*)d_ws + 64;
    float* dstv  = srcv + BN * NODES;
    short* WtHi  = (short*)(dstv + BN * NODES);
    short* WtLo  = WtHi + FDIM * FDIM;
    short* WhTHi = WtLo + FDIM * FDIM;
    short* WhTLo = WhTHi + (size_t)BN * FDIM * NODES;

    detect_kernel<<<1, 256, 0, stream>>>((const unsigned short*)h, flag);
    prep_w_kernel<<<dim3(16, 16), 256, 0, stream>>>(W, flag, WtHi, WtLo);
    wh_mfma_kernel<<<dim3(16, BN), 256, 0, stream>>>(h, WtHi, WtLo, a, flag,
                                                     WhTHi, WhTLo, srcv, dstv);
    attn_mfma_kernel<<<1024, 256, 0, stream>>>(WhTHi, WhTLo, srcv, dstv,
                                               adj, flag, d_out);
}

// Round 4
// 174.721 us; speedup vs baseline: 2.4575x; 1.2455x over previous
//
#include <hip/hip_runtime.h>
#include <hip/hip_bf16.h>

// GAT layer: B=8, N=8 (BN=64 batches), Nodes=512, IF=OF=256.
// MFMA on v_mfma_f32_16x16x32_bf16, split-bf16 (hi+lo) operands.
// Both GEMMs use the proven 2-phase shared-staging template:
//   stage(next) -> ds_read(cur) -> MFMA -> __syncthreads(), global_load_lds
//   with linear LDS dest + inverse-swizzled global source (XOR slot swizzle).
//
//  K0: detect dtype -> flag
//  KP: W -> Wt[f][k] bf16 hi/lo
//  KA: Wh = h@W. 512 blocks x 256 thr, 64 rows x 256 cols, K=256 (8 steps).
//      Writes WhT[bn][f][i] hi/lo + src/dst (fp32 accum path).
//  KB: fused softmax (wave/row, P -> swizzled LDS bf16) + out=elu((P@Wh)/s).
//      512 blocks x 512 thr, 64 rows, K=512 (16 steps), XCD-swizzled.

#define ALPHA 0.2f
#define MASK_VAL -9000000000000000.0f
#define NODES 512
#define FDIM 256
#define BN 64

typedef float  f32x4 __attribute__((ext_vector_type(4)));
typedef int    i32x4 __attribute__((ext_vector_type(4)));
typedef short  s16x8 __attribute__((ext_vector_type(8)));
typedef short  s16x4 __attribute__((ext_vector_type(4)));
typedef __bf16 bf16x8 __attribute__((ext_vector_type(8)));

__device__ __forceinline__ unsigned short f2bfu(float x) {
    __hip_bfloat16 b = __float2bfloat16(x);   // RNE
    unsigned short u; __builtin_memcpy(&u, &b, 2); return u;
}
__device__ __forceinline__ float bfu2f(unsigned short u) {
    unsigned int w = ((unsigned int)u) << 16; return __uint_as_float(w);
}
__device__ __forceinline__ f32x4 mfma16(s16x8 a, s16x8 b, f32x4 c) {
    return __builtin_amdgcn_mfma_f32_16x16x32_bf16(
        __builtin_bit_cast(bf16x8, a), __builtin_bit_cast(bf16x8, b), c, 0, 0, 0);
}

// hi/lo split of 8 fp32 (truncation split; residual ~2^-16 rel).
__device__ __forceinline__ void split8v(f32x4 v0, f32x4 v1, s16x8& hi, s16x8& lo)
{
    float x[8] = {v0[0], v0[1], v0[2], v0[3], v1[0], v1[1], v1[2], v1[3]};
    unsigned hw[4], lw[4];
    #pragma unroll
    for (int d = 0; d < 4; ++d) {
        const unsigned u0 = __float_as_uint(x[2*d]);
        const unsigned u1 = __float_as_uint(x[2*d + 1]);
        hw[d] = __builtin_amdgcn_perm(u1, u0, 0x07060302);
        const float l0 = x[2*d]     - __uint_as_float(u0 & 0xFFFF0000u);
        const float l1 = x[2*d + 1] - __uint_as_float(u1 & 0xFFFF0000u);
        lw[d] = __builtin_amdgcn_perm(__float_as_uint(l1), __float_as_uint(l0),
                                      0x07060302);
    }
    hi = __builtin_bit_cast(s16x8, *(unsigned(*)[4])hw);
    lo = __builtin_bit_cast(s16x8, *(unsigned(*)[4])lw);
}

__device__ __forceinline__ void gll16(const void* g, void* l) {
    __builtin_amdgcn_global_load_lds(
        (const __attribute__((address_space(1))) unsigned int*)g,
        (__attribute__((address_space(3))) unsigned int*)l,
        16, 0, 0);
}

// ---------------- K0: dtype detect ----------------
__global__ __launch_bounds__(256) void detect_kernel(const unsigned short* __restrict__ hraw,
                                                     int* __restrict__ flag)
{
    const int tid = threadIdx.x;
    float m = 0.0f;
    for (int i = tid; i < 16384; i += 256) {
        unsigned int w = ((unsigned int)hraw[i]) << 16;
        float v = __uint_as_float(w);
        v = fabsf(v);
        if (!(v == v)) v = 1e30f;
        m = fmaxf(m, v);
    }
    #pragma unroll
    for (int off = 32; off >= 1; off >>= 1)
        m = fmaxf(m, __shfl_down(m, off));
    __shared__ float red[4];
    if ((tid & 63) == 0) red[tid >> 6] = m;
    __syncthreads();
    if (tid == 0) {
        float mm = fmaxf(fmaxf(red[0], red[1]), fmaxf(red[2], red[3]));
        *flag = (mm > 1e4f) ? 1 : 0;
    }
}

// ---------------- KP: W -> Wt[f][k] bf16 hi/lo ----------------
__global__ __launch_bounds__(256) void prep_w_kernel(
    const void* __restrict__ Wv, const int* __restrict__ flagp,
    short* __restrict__ WtHi, short* __restrict__ WtLo)
{
    const int flag = *flagp;
    __shared__ float tile[16][17];
    const int tx = threadIdx.x & 15, ty = threadIdx.x >> 4;
    const int kk = blockIdx.y * 16 + ty;
    const int f  = blockIdx.x * 16 + tx;
    float v;
    if (flag) v = ((const float*)Wv)[kk * FDIM + f];
    else      v = bfu2f(((const unsigned short*)Wv)[kk * FDIM + f]);
    tile[ty][tx] = v;
    __syncthreads();
    const float x = tile[tx][ty];
    const int fo = blockIdx.x * 16 + ty;
    const int ko = blockIdx.y * 16 + tx;
    unsigned short h = f2bfu(x);
    WtHi[fo * FDIM + ko] = (short)h;
    WtLo[fo * FDIM + ko] = (short)f2bfu(x - bfu2f(h));  // exact 0 in bf16 mode
}

// ---------------- KA: Wh = h@W ----------------
// 512 blocks x 256 thr (4 waves, 2 blocks/CU). 64 rows x 256 cols, K=256.
// Wave w -> cols w*64..+64; all 64 rows (4 row-tiles). acc[4][4].
__global__ __launch_bounds__(256, 2) void wh_gemm(
    const void* __restrict__ hv,
    const short* __restrict__ WtHi, const short* __restrict__ WtLo,
    const void* __restrict__ av, const int* __restrict__ flagp,
    short* __restrict__ WhTHi, short* __restrict__ WhTLo,
    float* __restrict__ srcv, float* __restrict__ dstv)
{
    __shared__ __align__(16) char smem[81920];
    char* As = smem;            // [2][8192]: fp32 [64][8 seg]; bf16 [2][4096]
    char* Bh = smem + 16384;    // [2][16384]: [256 f][4 seg]
    char* Bl = smem + 49152;    // [2][16384]

    const int flag = *flagp;
    const int blk = blockIdx.x;
    const int bn  = blk >> 3;
    const int i0  = (blk & 7) * 64;
    const size_t r0g = (size_t)blk * 64;
    const int tid = threadIdx.x;
    const int w = tid >> 6, l = tid & 63;
    const int fb = l & 15, g = l >> 4;
    const unsigned wub = (unsigned)(tid & ~63);   // wave-uniform lane base

    f32x4 acc[4][4];
    #pragma unroll
    for (int rt = 0; rt < 4; ++rt)
        #pragma unroll
        for (int ct = 0; ct < 4; ++ct) acc[rt][ct] = f32x4{0.f,0.f,0.f,0.f};

    // staging: LDS dest linear (idx*16), global seg = slot ^ swz (involution)
    auto stageBhl = [&](int buf, int k0) {
        #pragma unroll
        for (int i = 0; i < 4; ++i) {
            const int idx = i * 256 + tid;          // 0..1023
            const int f = idx >> 2, sg = idx & 3;
            const int ss = sg ^ ((f ^ (f >> 2)) & 3);
            char* d = (char*)(size_t)((i * 256 + (int)wub) * 16);
            gll16(WtHi + f * FDIM + k0 + ss * 8, Bh + buf * 16384 + (size_t)d);
            gll16(WtLo + f * FDIM + k0 + ss * 8, Bl + buf * 16384 + (size_t)d);
        }
    };
    auto stageBh = [&](int buf, int k0) {
        #pragma unroll
        for (int i = 0; i < 4; ++i) {
            const int idx = i * 256 + tid;
            const int f = idx >> 2, sg = idx & 3;
            const int ss = sg ^ ((f ^ (f >> 2)) & 3);
            gll16(WtHi + f * FDIM + k0 + ss * 8,
                  Bh + buf * 16384 + (i * 256 + (int)wub) * 16);
        }
    };
    auto stageAf = [&](int buf, int k0) {
        #pragma unroll
        for (int i = 0; i < 2; ++i) {
            const int idx = i * 256 + tid;          // 0..511
            const int row = idx >> 3, sg = idx & 7;
            const int ss = sg ^ (row & 7);
            gll16((const float*)hv + (r0g + row) * FDIM + k0 + ss * 4,
                  As + buf * 8192 + (i * 256 + (int)wub) * 16);
        }
    };
    auto stageAb = [&](int buf, int k0) {
        const int row = tid >> 2, sg = tid & 3;
        const int ss = sg ^ ((row >> 1) & 3);
        gll16((const short*)hv + (r0g + row) * FDIM + k0 + ss * 8,
              As + buf * 4096 + (int)wub * 16);
    };

    if (flag) {
        stageAf(0, 0); stageBhl(0, 0);
        __syncthreads();
        for (int t = 0; t < 8; ++t) {
            const int cur = t & 1, nxt = cur ^ 1;
            if (t < 7) { stageAf(nxt, (t + 1) * 32); stageBhl(nxt, (t + 1) * 32); }
            s16x8 bhf[4], blf[4];
            #pragma unroll
            for (int ct = 0; ct < 4; ++ct) {
                const int f = w * 64 + ct * 16 + fb;
                const int slot = g ^ ((f ^ (f >> 2)) & 3);
                const unsigned off = (unsigned)(cur * 16384 + f * 64 + slot * 16);
                bhf[ct] = *(const s16x8*)(Bh + off);
                blf[ct] = *(const s16x8*)(Bl + off);
            }
            #pragma unroll
            for (int rt = 0; rt < 4; ++rt) {
                const int row = rt * 16 + fb;
                const int s0 = (2 * g) ^ (row & 7), s1 = (2 * g + 1) ^ (row & 7);
                const f32x4 v0 = *(const f32x4*)(As + cur * 8192 + row * 128 + s0 * 16);
                const f32x4 v1 = *(const f32x4*)(As + cur * 8192 + row * 128 + s1 * 16);
                s16x8 ah, al; split8v(v0, v1, ah, al);
                #pragma unroll
                for (int ct = 0; ct < 4; ++ct) {
                    acc[rt][ct] = mfma16(ah, bhf[ct], acc[rt][ct]);
                    acc[rt][ct] = mfma16(al, bhf[ct], acc[rt][ct]);
                    acc[rt][ct] = mfma16(ah, blf[ct], acc[rt][ct]);
                }
            }
            __syncthreads();
        }
    } else {
        stageAb(0, 0); stageBh(0, 0);
        __syncthreads();
        for (int t = 0; t < 8; ++t) {
            const int cur = t & 1, nxt = cur ^ 1;
            if (t < 7) { stageAb(nxt, (t + 1) * 32); stageBh(nxt, (t + 1) * 32); }
            s16x8 bhf[4];
            #pragma unroll
            for (int ct = 0; ct < 4; ++ct) {
                const int f = w * 64 + ct * 16 + fb;
                const int slot = g ^ ((f ^ (f >> 2)) & 3);
                bhf[ct] = *(const s16x8*)(Bh + cur * 16384 + f * 64 + slot * 16);
            }
            #pragma unroll
            for (int rt = 0; rt < 4; ++rt) {
                const int row = rt * 16 + fb;
                const int slot = g ^ ((row >> 1) & 3);
                const s16x8 a = *(const s16x8*)(As + cur * 4096 + row * 64 + slot * 16);
                #pragma unroll
                for (int ct = 0; ct < 4; ++ct)
                    acc[rt][ct] = mfma16(a, bhf[ct], acc[rt][ct]);
            }
            __syncthreads();
        }
    }

    // Write WhT[bn][f][i] hi/lo. D: row = rt*16 + g*4 + r, col = f.
    const size_t wbT = (size_t)bn * FDIM * NODES;
    #pragma unroll
    for (int rt = 0; rt < 4; ++rt) {
        const int orow = i0 + rt * 16 + g * 4;
        #pragma unroll
        for (int ct = 0; ct < 4; ++ct) {
            const int f = w * 64 + ct * 16 + fb;
            s16x4 h4, l4;
            #pragma unroll
            for (int r = 0; r < 4; ++r) {
                float x = acc[rt][ct][r];
                unsigned short hh = f2bfu(x);
                h4[r] = (short)hh;
                l4[r] = (short)f2bfu(x - bfu2f(hh));
            }
            *(s16x4*)(WhTHi + wbT + (size_t)f * NODES + orow) = h4;
            *(s16x4*)(WhTLo + wbT + (size_t)f * NODES + orow) = l4;
        }
    }

    // src/dst: in-wave reduce over 16 col-lanes, cross-wave via LDS (aliases As).
    float a1v[4], a2v[4];
    #pragma unroll
    for (int ct = 0; ct < 4; ++ct) {
        const int f = w * 64 + ct * 16 + fb;
        if (flag) {
            a1v[ct] = ((const float*)av)[f];
            a2v[ct] = ((const float*)av)[FDIM + f];
        } else {
            a1v[ct] = bfu2f(((const unsigned short*)av)[f]);
            a2v[ct] = bfu2f(((const unsigned short*)av)[FDIM + f]);
        }
    }
    float* red1 = (float*)smem;          // [4][64] (A bufs dead after K-loop)
    float* red2 = red1 + 256;
    #pragma unroll
    for (int rt = 0; rt < 4; ++rt) {
        #pragma unroll
        for (int r = 0; r < 4; ++r) {
            float s1 = 0.f, s2 = 0.f;
            #pragma unroll
            for (int ct = 0; ct < 4; ++ct) {
                s1 = fmaf(acc[rt][ct][r], a1v[ct], s1);
                s2 = fmaf(acc[rt][ct][r], a2v[ct], s2);
            }
            #pragma unroll
            for (int off = 1; off <= 8; off <<= 1) {
                s1 += __shfl_xor(s1, off);
                s2 += __shfl_xor(s2, off);
            }
            if (fb == 0) {
                red1[w * 64 + rt * 16 + g * 4 + r] = s1;
                red2[w * 64 + rt * 16 + g * 4 + r] = s2;
            }
        }
    }
    __syncthreads();
    if (tid < 64) {
        srcv[bn * NODES + i0 + tid] =
            red1[tid] + red1[64 + tid] + red1[128 + tid] + red1[192 + tid];
        dstv[bn * NODES + i0 + tid] =
            red2[tid] + red2[64 + tid] + red2[128 + tid] + red2[192 + tid];
    }
}

// ---------------- KB: fused softmax + att@Wh + elu ----------------
// 512 blocks (XCD-swizzled) x 512 thr (8 waves). 64 rows, 256 f, K=512.
// P lives in LDS (bf16, seg-XOR swizzled) and is read directly as A-frags.
// B (WhT hi/lo) double-buffered via global_load_lds, 2-phase loop.
__global__ __launch_bounds__(512, 2) void pv_gemm(
    const short* __restrict__ WhTHi, const short* __restrict__ WhTLo,
    const float* __restrict__ srcv, const float* __restrict__ dstv,
    const int* __restrict__ adj, const int* __restrict__ flagp,
    void* __restrict__ out)
{
    __shared__ __align__(16) char smem[131328];
    char* Ps = smem;                 // [64 rows][64 seg x 16B] swizzled
    char* Bh = smem + 65536;         // [2][16384]
    char* Bl = smem + 98304;         // [2][16384]
    float* rowinvS = (float*)(smem + 131072);   // [64]

    const int flag = *flagp;
    const int b0 = blockIdx.x;
    const int blk = (b0 & 7) * 64 + (b0 >> 3);   // bijective: 512 % 8 == 0
    const int bn  = blk >> 3;
    const int i0  = (blk & 7) * 64;
    const int tid = threadIdx.x;
    const int w = tid >> 6, l = tid & 63;
    const unsigned wub = (unsigned)(tid & ~63);

    const short* bhig = WhTHi + (size_t)bn * FDIM * NODES;
    const short* blog = WhTLo + (size_t)bn * FDIM * NODES;

    auto stageB = [&](int buf, int k0) {
        #pragma unroll
        for (int i = 0; i < 2; ++i) {
            const int idx = i * 512 + tid;          // 0..1023
            const int f = idx >> 2, sg = idx & 3;
            const int ss = sg ^ ((f ^ (f >> 2)) & 3);
            const int d = (i * 512 + (int)wub) * 16;
            gll16(bhig + (size_t)f * NODES + k0 + ss * 8, Bh + buf * 16384 + d);
            gll16(blog + (size_t)f * NODES + k0 + ss * 8, Bl + buf * 16384 + d);
        }
    };

    stageB(0, 0);   // lands while softmax runs

    // ---- softmax: wave per row (8 rows/wave), lane l covers j=8l..8l+8 ----
    {
        const float* drow = dstv + bn * NODES;
        const int j = l * 8;
        for (int rr = 0; rr < 8; ++rr) {
            const int r = w * 8 + rr;
            const int* adjrow = adj + (size_t)(i0 + r) * NODES;
            const float srow = srcv[bn * NODES + i0 + r];
            const i32x4 q0 = *(const i32x4*)(adjrow + j);
            const i32x4 q1 = *(const i32x4*)(adjrow + j + 4);
            const f32x4 d0 = *(const f32x4*)(drow + j);
            const f32x4 d1 = *(const f32x4*)(drow + j + 4);
            float e[8];
            #pragma unroll
            for (int k = 0; k < 4; ++k) {
                float ev = srow + d0[k];
                ev = (ev > 0.f) ? ev : ALPHA * ev;
                e[k] = (q0[k] > 0) ? ev : MASK_VAL;
                float ew = srow + d1[k];
                ew = (ew > 0.f) ? ew : ALPHA * ew;
                e[4 + k] = (q1[k] > 0) ? ew : MASK_VAL;
            }
            float m = e[0];
            #pragma unroll
            for (int k = 1; k < 8; ++k) m = fmaxf(m, e[k]);
            #pragma unroll
            for (int off = 1; off <= 32; off <<= 1) m = fmaxf(m, __shfl_xor(m, off));
            float s = 0.f;
            s16x8 ph;
            #pragma unroll
            for (int k = 0; k < 8; ++k) {
                float p = __expf(e[k] - m);   // masked -> 0; all-masked row -> 1
                s += p;
                ph[k] = (short)f2bfu(p);
            }
            #pragma unroll
            for (int off = 1; off <= 32; off <<= 1) s += __shfl_xor(s, off);
            // seg l stored at slot l ^ (r&7)
            *(s16x8*)(Ps + r * 1024 + ((l ^ (r & 7)) * 16)) = ph;
            if (l == 0) rowinvS[r] = 1.0f / s;
        }
    }
    __syncthreads();   // P ready; B buf0 staged (vmcnt drained by barrier)

    // ---- PV GEMM: 16 K-steps, 2-phase ----
    const int fb = l & 15, g = l >> 4;
    const int wr = w >> 2, wc = w & 3;

    f32x4 acc[2][4];
    #pragma unroll
    for (int rt = 0; rt < 2; ++rt)
        #pragma unroll
        for (int ct = 0; ct < 4; ++ct) acc[rt][ct] = f32x4{0.f,0.f,0.f,0.f};

    for (int t = 0; t < 16; ++t) {
        const int cur = t & 1, nxt = cur ^ 1;
        if (t < 15) stageB(nxt, (t + 1) * 32);
        s16x8 bhf[4], blf[4];
        #pragma unroll
        for (int ct = 0; ct < 4; ++ct) {
            const int f = wc * 64 + ct * 16 + fb;
            const int slot = g ^ ((f ^ (f >> 2)) & 3);
            const unsigned off = (unsigned)(cur * 16384 + f * 64 + slot * 16);
            bhf[ct] = *(const s16x8*)(Bh + off);
            blf[ct] = *(const s16x8*)(Bl + off);
        }
        s16x8 af[2];
        #pragma unroll
        for (int rt = 0; rt < 2; ++rt) {
            const int row = wr * 32 + rt * 16 + fb;
            const int seg = 4 * t + g;
            af[rt] = *(const s16x8*)(Ps + row * 1024 + ((seg ^ (row & 7)) * 16));
        }
        #pragma unroll
        for (int rt = 0; rt < 2; ++rt)
            #pragma unroll
            for (int ct = 0; ct < 4; ++ct) {
                acc[rt][ct] = mfma16(af[rt], bhf[ct], acc[rt][ct]);
                acc[rt][ct] = mfma16(af[rt], blf[ct], acc[rt][ct]);
            }
        __syncthreads();
    }

    // epilogue: scale by 1/rowsum, elu, store
    #pragma unroll
    for (int rt = 0; rt < 2; ++rt) {
        const int rbase = wr * 32 + rt * 16 + g * 4;
        float inv[4];
        #pragma unroll
        for (int r = 0; r < 4; ++r) inv[r] = rowinvS[rbase + r];
        #pragma unroll
        for (int ct = 0; ct < 4; ++ct) {
            const int f = wc * 64 + ct * 16 + fb;
            #pragma unroll
            for (int r = 0; r < 4; ++r) {
                float v = acc[rt][ct][r] * inv[r];
                v = (v > 0.f) ? v : expm1f(v);
                const size_t o = ((size_t)bn * NODES + i0 + rbase + r) * FDIM + f;
                if (flag) ((float*)out)[o] = v;
                else      ((unsigned short*)out)[o] = f2bfu(v);
            }
        }
    }
}

extern "C" void kernel_launch(void* const* d_in, const int* in_sizes, int n_in,
                              void* d_out, int out_size, void* d_ws, size_t ws_size,
                              hipStream_t stream)
{
    const void* h   = d_in[0];
    const int*  adj = (const int*)d_in[1];
    const void* W   = d_in[2];
    const void* a   = d_in[3];

    // ws layout: flag 256B | src 128K | dst 128K | WtHi 128K | WtLo 128K
    //            | WhTHi 16.78M | WhTLo 16.78M   (~34.1 MB total)
    int*   flag  = (int*)d_ws;
    float* srcv  = (float*)d_ws + 64;
    float* dstv  = srcv + BN * NODES;
    short* WtHi  = (short*)(dstv + BN * NODES);
    short* WtLo  = WtHi + FDIM * FDIM;
    short* WhTHi = WtLo + FDIM * FDIM;
    short* WhTLo = WhTHi + (size_t)BN * FDIM * NODES;

    detect_kernel<<<1, 256, 0, stream>>>((const unsigned short*)h, flag);
    prep_w_kernel<<<dim3(16, 16), 256, 0, stream>>>(W, flag, WtHi, WtLo);
    wh_gemm<<<512, 256, 0, stream>>>(h, WtHi, WtLo, a, flag,
                                     WhTHi, WhTLo, srcv, dstv);
    pv_gemm<<<512, 512, 0, stream>>>(WhTHi, WhTLo, srcv, dstv, adj, flag, d_out);
}

// Round 5
// 164.055 us; speedup vs baseline: 2.6173x; 1.0650x over previous
//
#include <hip/hip_runtime.h>
#include <hip/hip_bf16.h>

// GAT layer: B=8, N=8 (BN=64 batches), Nodes=512, IF=OF=256.
// MFMA on v_mfma_f32_16x16x32_bf16, split-bf16 (hi+lo) operands.
//
//  K0: detect dtype -> flag
//  KP: W -> Wt[f][k] bf16 hi/lo
//  KA: Wh = h@W. 512 blocks x 256 thr (2 blocks/CU). A reg-staged (split once
//      at stage time), B via global_load_lds double-buffer, 2-phase barriers.
//  KB: fused softmax (P stored pre-normalized bf16 in LDS) + out=elu(P@Wh).
//      512 blocks x 1024 thr, 3-buffer counted-vmcnt pipeline (T3+T4) with
//      raw s_barrier + s_setprio around MFMA (T5). XCD-swizzled.

#define ALPHA 0.2f
#define MASK_VAL -9000000000000000.0f
#define NODES 512
#define FDIM 256
#define BN 64

typedef float  f32x4 __attribute__((ext_vector_type(4)));
typedef int    i32x4 __attribute__((ext_vector_type(4)));
typedef short  s16x8 __attribute__((ext_vector_type(8)));
typedef short  s16x4 __attribute__((ext_vector_type(4)));
typedef __bf16 bf16x8 __attribute__((ext_vector_type(8)));

__device__ __forceinline__ unsigned short f2bfu(float x) {
    __hip_bfloat16 b = __float2bfloat16(x);   // RNE
    unsigned short u; __builtin_memcpy(&u, &b, 2); return u;
}
__device__ __forceinline__ float bfu2f(unsigned short u) {
    unsigned int w = ((unsigned int)u) << 16; return __uint_as_float(w);
}
__device__ __forceinline__ f32x4 mfma16(s16x8 a, s16x8 b, f32x4 c) {
    return __builtin_amdgcn_mfma_f32_16x16x32_bf16(
        __builtin_bit_cast(bf16x8, a), __builtin_bit_cast(bf16x8, b), c, 0, 0, 0);
}

// hi/lo split of 8 fp32 (truncation split; residual ~2^-16 rel).
__device__ __forceinline__ void split8v(f32x4 v0, f32x4 v1, s16x8& hi, s16x8& lo)
{
    float x[8] = {v0[0], v0[1], v0[2], v0[3], v1[0], v1[1], v1[2], v1[3]};
    unsigned hw[4], lw[4];
    #pragma unroll
    for (int d = 0; d < 4; ++d) {
        const unsigned u0 = __float_as_uint(x[2*d]);
        const unsigned u1 = __float_as_uint(x[2*d + 1]);
        hw[d] = __builtin_amdgcn_perm(u1, u0, 0x07060302);
        const float l0 = x[2*d]     - __uint_as_float(u0 & 0xFFFF0000u);
        const float l1 = x[2*d + 1] - __uint_as_float(u1 & 0xFFFF0000u);
        lw[d] = __builtin_amdgcn_perm(__float_as_uint(l1), __float_as_uint(l0),
                                      0x07060302);
    }
    hi = __builtin_bit_cast(s16x8, *(unsigned(*)[4])hw);
    lo = __builtin_bit_cast(s16x8, *(unsigned(*)[4])lw);
}

__device__ __forceinline__ void gll16(const void* g, void* l) {
    __builtin_amdgcn_global_load_lds(
        (const __attribute__((address_space(1))) unsigned int*)g,
        (__attribute__((address_space(3))) unsigned int*)l,
        16, 0, 0);
}

// ---------------- K0: dtype detect ----------------
__global__ __launch_bounds__(256) void detect_kernel(const unsigned short* __restrict__ hraw,
                                                     int* __restrict__ flag)
{
    const int tid = threadIdx.x;
    float m = 0.0f;
    for (int i = tid; i < 16384; i += 256) {
        unsigned int w = ((unsigned int)hraw[i]) << 16;
        float v = __uint_as_float(w);
        v = fabsf(v);
        if (!(v == v)) v = 1e30f;
        m = fmaxf(m, v);
    }
    #pragma unroll
    for (int off = 32; off >= 1; off >>= 1)
        m = fmaxf(m, __shfl_down(m, off));
    __shared__ float red[4];
    if ((tid & 63) == 0) red[tid >> 6] = m;
    __syncthreads();
    if (tid == 0) {
        float mm = fmaxf(fmaxf(red[0], red[1]), fmaxf(red[2], red[3]));
        *flag = (mm > 1e4f) ? 1 : 0;
    }
}

// ---------------- KP: W -> Wt[f][k] bf16 hi/lo ----------------
__global__ __launch_bounds__(256) void prep_w_kernel(
    const void* __restrict__ Wv, const int* __restrict__ flagp,
    short* __restrict__ WtHi, short* __restrict__ WtLo)
{
    const int flag = *flagp;
    __shared__ float tile[16][17];
    const int tx = threadIdx.x & 15, ty = threadIdx.x >> 4;
    const int kk = blockIdx.y * 16 + ty;
    const int f  = blockIdx.x * 16 + tx;
    float v;
    if (flag) v = ((const float*)Wv)[kk * FDIM + f];
    else      v = bfu2f(((const unsigned short*)Wv)[kk * FDIM + f]);
    tile[ty][tx] = v;
    __syncthreads();
    const float x = tile[tx][ty];
    const int fo = blockIdx.x * 16 + ty;
    const int ko = blockIdx.y * 16 + tx;
    unsigned short h = f2bfu(x);
    WtHi[fo * FDIM + ko] = (short)h;
    WtLo[fo * FDIM + ko] = (short)f2bfu(x - bfu2f(h));  // exact 0 in bf16 mode
}

// ---------------- KA: Wh = h@W ----------------
// 512 blocks x 256 thr (4 waves, 2 blocks/CU). 64 rows x 256 cols, K=256.
// LDS: A [2 buf][hi 4K | lo 4K] at [0,16K); Bh [2][16K) at 16K; Bl at 48K.
__global__ __launch_bounds__(256, 2) void wh_gemm(
    const void* __restrict__ hv,
    const short* __restrict__ WtHi, const short* __restrict__ WtLo,
    const void* __restrict__ av, const int* __restrict__ flagp,
    short* __restrict__ WhTHi, short* __restrict__ WhTLo,
    float* __restrict__ srcv, float* __restrict__ dstv)
{
    __shared__ __align__(16) char smem[81920];

    const int flag = *flagp;
    const int blk = blockIdx.x;
    const int bn  = blk >> 3;
    const int i0  = (blk & 7) * 64;
    const size_t r0g = (size_t)blk * 64;
    const int tid = threadIdx.x;
    const int w = tid >> 6, l = tid & 63;
    const int fb = l & 15, g = l >> 4;

    // A staging map: thread -> (row, seg-slot); global seg XOR-permuted so
    // read-side slot = g ^ ((row>>1)&3) is conflict-free (<=2-way).
    const int arow = tid >> 2, asg = tid & 3;
    const int aseg = asg ^ ((arow >> 1) & 3);
    const int awr  = arow * 64 + asg * 16;   // LDS byte off within A buf (hi)

    // B staging map: 4 (f, seg) pairs per thread, pointers precomputed.
    const short* gBh[4];
    const short* gBl[4];
    int bdst[4];
    {
        const int bsg = tid & 3;
        #pragma unroll
        for (int i = 0; i < 4; ++i) {
            const int f = i * 64 + (tid >> 2);
            const int ss = bsg ^ ((f ^ (f >> 2)) & 3);
            gBh[i] = WtHi + f * FDIM + ss * 8;
            gBl[i] = WtLo + f * FDIM + ss * 8;
            bdst[i] = (i * 256 + tid) * 16;
        }
    }

    f32x4 acc[4][4];
    #pragma unroll
    for (int rt = 0; rt < 4; ++rt)
        #pragma unroll
        for (int ct = 0; ct < 4; ++ct) acc[rt][ct] = f32x4{0.f,0.f,0.f,0.f};

    if (flag) {
        const float* gA = (const float*)hv + (r0g + arow) * FDIM + aseg * 8;
        {   // prologue: A(0) reg-stage + split, B(0) gll
            f32x4 v0 = *(const f32x4*)gA;
            f32x4 v1 = *(const f32x4*)(gA + 4);
            #pragma unroll
            for (int i = 0; i < 4; ++i) {
                gll16(gBh[i], smem + 16384 + bdst[i]);
                gll16(gBl[i], smem + 49152 + bdst[i]);
            }
            s16x8 hi, lo; split8v(v0, v1, hi, lo);
            *(s16x8*)(smem + awr) = hi;
            *(s16x8*)(smem + 4096 + awr) = lo;
        }
        __syncthreads();
        for (int t = 0; t < 8; ++t) {
            const int cur = t & 1, nxt = cur ^ 1;
            f32x4 v0 = {}, v1 = {};
            if (t < 7) {
                v0 = *(const f32x4*)(gA + (t+1)*32);
                v1 = *(const f32x4*)(gA + (t+1)*32 + 4);
                #pragma unroll
                for (int i = 0; i < 4; ++i) {
                    gll16(gBh[i] + (t+1)*32, smem + 16384 + nxt*16384 + bdst[i]);
                    gll16(gBl[i] + (t+1)*32, smem + 49152 + nxt*16384 + bdst[i]);
                }
            }
            s16x8 bh[4], bl[4], ah[4], al[4];
            #pragma unroll
            for (int ct = 0; ct < 4; ++ct) {
                const int f = w*64 + ct*16 + fb;
                const int slot = g ^ ((f ^ (f >> 2)) & 3);
                const int off = 16384 + cur*16384 + f*64 + slot*16;
                bh[ct] = *(const s16x8*)(smem + off);
                bl[ct] = *(const s16x8*)(smem + off + 32768);
            }
            #pragma unroll
            for (int rt = 0; rt < 4; ++rt) {
                const int row = rt*16 + fb;
                const int slot = g ^ ((row >> 1) & 3);
                const int off = cur*8192 + row*64 + slot*16;
                ah[rt] = *(const s16x8*)(smem + off);
                al[rt] = *(const s16x8*)(smem + off + 4096);
            }
            __builtin_amdgcn_s_setprio(1);
            #pragma unroll
            for (int rt = 0; rt < 4; ++rt)
                #pragma unroll
                for (int ct = 0; ct < 4; ++ct) {
                    acc[rt][ct] = mfma16(ah[rt], bh[ct], acc[rt][ct]);
                    acc[rt][ct] = mfma16(al[rt], bh[ct], acc[rt][ct]);
                    acc[rt][ct] = mfma16(ah[rt], bl[ct], acc[rt][ct]);
                }
            __builtin_amdgcn_s_setprio(0);
            if (t < 7) {
                s16x8 hi, lo; split8v(v0, v1, hi, lo);
                *(s16x8*)(smem + nxt*8192 + awr) = hi;
                *(s16x8*)(smem + nxt*8192 + 4096 + awr) = lo;
            }
            __syncthreads();
        }
    } else {
        const short* gA = (const short*)hv + (r0g + arow) * FDIM + aseg * 8;
        {
            s16x8 a0 = *(const s16x8*)gA;
            #pragma unroll
            for (int i = 0; i < 4; ++i) gll16(gBh[i], smem + 16384 + bdst[i]);
            *(s16x8*)(smem + awr) = a0;
        }
        __syncthreads();
        for (int t = 0; t < 8; ++t) {
            const int cur = t & 1, nxt = cur ^ 1;
            s16x8 an = {};
            if (t < 7) {
                an = *(const s16x8*)(gA + (t+1)*32);
                #pragma unroll
                for (int i = 0; i < 4; ++i)
                    gll16(gBh[i] + (t+1)*32, smem + 16384 + nxt*16384 + bdst[i]);
            }
            s16x8 bh[4], ah[4];
            #pragma unroll
            for (int ct = 0; ct < 4; ++ct) {
                const int f = w*64 + ct*16 + fb;
                const int slot = g ^ ((f ^ (f >> 2)) & 3);
                bh[ct] = *(const s16x8*)(smem + 16384 + cur*16384 + f*64 + slot*16);
            }
            #pragma unroll
            for (int rt = 0; rt < 4; ++rt) {
                const int row = rt*16 + fb;
                const int slot = g ^ ((row >> 1) & 3);
                ah[rt] = *(const s16x8*)(smem + cur*8192 + row*64 + slot*16);
            }
            __builtin_amdgcn_s_setprio(1);
            #pragma unroll
            for (int rt = 0; rt < 4; ++rt)
                #pragma unroll
                for (int ct = 0; ct < 4; ++ct)
                    acc[rt][ct] = mfma16(ah[rt], bh[ct], acc[rt][ct]);
            __builtin_amdgcn_s_setprio(0);
            if (t < 7) *(s16x8*)(smem + nxt*8192 + awr) = an;
            __syncthreads();
        }
    }

    // Write WhT[bn][f][i] hi/lo. D: row = rt*16 + g*4 + r, col = f.
    const size_t wbT = (size_t)bn * FDIM * NODES;
    #pragma unroll
    for (int rt = 0; rt < 4; ++rt) {
        const int orow = i0 + rt * 16 + g * 4;
        #pragma unroll
        for (int ct = 0; ct < 4; ++ct) {
            const int f = w * 64 + ct * 16 + fb;
            s16x4 h4, l4;
            #pragma unroll
            for (int r = 0; r < 4; ++r) {
                float x = acc[rt][ct][r];
                unsigned short hh = f2bfu(x);
                h4[r] = (short)hh;
                l4[r] = (short)f2bfu(x - bfu2f(hh));
            }
            *(s16x4*)(WhTHi + wbT + (size_t)f * NODES + orow) = h4;
            *(s16x4*)(WhTLo + wbT + (size_t)f * NODES + orow) = l4;
        }
    }

    // src/dst reduction (fp32 accumulator path, same as r4).
    float a1v[4], a2v[4];
    #pragma unroll
    for (int ct = 0; ct < 4; ++ct) {
        const int f = w * 64 + ct * 16 + fb;
        if (flag) {
            a1v[ct] = ((const float*)av)[f];
            a2v[ct] = ((const float*)av)[FDIM + f];
        } else {
            a1v[ct] = bfu2f(((const unsigned short*)av)[f]);
            a2v[ct] = bfu2f(((const unsigned short*)av)[FDIM + f]);
        }
    }
    float* red1 = (float*)smem;          // aliases dead A bufs
    float* red2 = red1 + 256;
    #pragma unroll
    for (int rt = 0; rt < 4; ++rt) {
        #pragma unroll
        for (int r = 0; r < 4; ++r) {
            float s1 = 0.f, s2 = 0.f;
            #pragma unroll
            for (int ct = 0; ct < 4; ++ct) {
                s1 = fmaf(acc[rt][ct][r], a1v[ct], s1);
                s2 = fmaf(acc[rt][ct][r], a2v[ct], s2);
            }
            #pragma unroll
            for (int off = 1; off <= 8; off <<= 1) {
                s1 += __shfl_xor(s1, off);
                s2 += __shfl_xor(s2, off);
            }
            if (fb == 0) {
                red1[w * 64 + rt * 16 + g * 4 + r] = s1;
                red2[w * 64 + rt * 16 + g * 4 + r] = s2;
            }
        }
    }
    __syncthreads();
    if (tid < 64) {
        srcv[bn * NODES + i0 + tid] =
            red1[tid] + red1[64 + tid] + red1[128 + tid] + red1[192 + tid];
        dstv[bn * NODES + i0 + tid] =
            red2[tid] + red2[64 + tid] + red2[128 + tid] + red2[192 + tid];
    }
}

// ---------------- KB: fused softmax + att@Wh + elu ----------------
// 512 blocks (XCD-swizzled) x 1024 thr (16 waves, 4x4 grid). 64 rows, K=512.
// Ps [64][64 slots x 16B] pre-normalized bf16 (64K); B 3 bufs x (hi16K+lo16K).
// K-loop: counted vmcnt(2) -> raw s_barrier -> stage(t+2) -> reads -> MFMA.
__global__ __launch_bounds__(1024, 4) void pv_gemm(
    const short* __restrict__ WhTHi, const short* __restrict__ WhTLo,
    const float* __restrict__ srcv, const float* __restrict__ dstv,
    const int* __restrict__ adj, const int* __restrict__ flagp,
    void* __restrict__ out)
{
    __shared__ __align__(16) char smem[163840];   // exactly 160 KiB

    const int flag = *flagp;
    const int b0 = blockIdx.x;
    const int blk = (b0 & 7) * 64 + (b0 >> 3);   // bijective: 512 % 8 == 0
    const int bn  = blk >> 3;
    const int i0  = (blk & 7) * 64;
    const int tid = threadIdx.x;
    const int w = tid >> 6, l = tid & 63;

    const short* bhig = WhTHi + (size_t)bn * FDIM * NODES;
    const short* blog = WhTLo + (size_t)bn * FDIM * NODES;

    // B staging map: thread -> (f = tid>>2, seg-slot tid&3), XOR-permuted src.
    const int sf = tid >> 2, ssg = tid & 3;
    const int sss = ssg ^ ((sf ^ (sf >> 2)) & 3);
    const short* gH = bhig + (size_t)sf * NODES + sss * 8;
    const short* gL = blog + (size_t)sf * NODES + sss * 8;
    char* ldsH = smem + 65536 + tid * 16;
    char* ldsL = smem + 65536 + 16384 + tid * 16;

    // prologue: stage k-steps 0,1 into bufs 0,1 (land during softmax)
    gll16(gH,      ldsH);          gll16(gL,      ldsL);
    gll16(gH + 32, ldsH + 32768);  gll16(gL + 32, ldsL + 32768);

    // ---- softmax: wave w -> rows w*4..w*4+4; lane l covers j = 8l..8l+8 ----
    {
        const float* drow = dstv + bn * NODES;
        const int j = l * 8;
        #pragma unroll
        for (int rr = 0; rr < 4; ++rr) {
            const int r = w * 4 + rr;
            const int* adjrow = adj + (size_t)(i0 + r) * NODES;
            const float srow = srcv[bn * NODES + i0 + r];
            const i32x4 q0 = *(const i32x4*)(adjrow + j);
            const i32x4 q1 = *(const i32x4*)(adjrow + j + 4);
            const f32x4 d0 = *(const f32x4*)(drow + j);
            const f32x4 d1 = *(const f32x4*)(drow + j + 4);
            float e[8];
            #pragma unroll
            for (int k = 0; k < 4; ++k) {
                float ev = srow + d0[k];
                ev = (ev > 0.f) ? ev : ALPHA * ev;
                e[k] = (q0[k] > 0) ? ev : MASK_VAL;
                float ew = srow + d1[k];
                ew = (ew > 0.f) ? ew : ALPHA * ew;
                e[4 + k] = (q1[k] > 0) ? ew : MASK_VAL;
            }
            float m = e[0];
            #pragma unroll
            for (int k = 1; k < 8; ++k) m = fmaxf(m, e[k]);
            #pragma unroll
            for (int off = 1; off <= 32; off <<= 1) m = fmaxf(m, __shfl_xor(m, off));
            float p[8], s = 0.f;
            #pragma unroll
            for (int k = 0; k < 8; ++k) {
                p[k] = __expf(e[k] - m);   // masked -> 0; all-masked row -> 1
                s += p[k];
            }
            #pragma unroll
            for (int off = 1; off <= 32; off <<= 1) s += __shfl_xor(s, off);
            const float isum = 1.0f / s;
            s16x8 ph;
            #pragma unroll
            for (int k = 0; k < 8; ++k) ph[k] = (short)f2bfu(p[k] * isum);
            // seg l stored at slot l ^ (r&7)
            *(s16x8*)(smem + r * 1024 + ((l ^ (r & 7)) * 16)) = ph;
        }
    }
    __syncthreads();

    // ---- PV GEMM: 16 K-steps, 3-buf counted-vmcnt pipeline ----
    const int fb = l & 15, g = l >> 4;
    const int wr = w >> 2, wc = w & 3;
    const int arow = wr * 16 + fb;
    const unsigned abase = (unsigned)(arow * 1024);
    const unsigned aswz  = (unsigned)((arow & 7) << 4);

    f32x4 acc[4];
    #pragma unroll
    for (int ct = 0; ct < 4; ++ct) acc[ct] = f32x4{0.f, 0.f, 0.f, 0.f};

    unsigned boff[4];
    #pragma unroll
    for (int ct = 0; ct < 4; ++ct) {
        const int f = wc * 64 + ct * 16 + fb;
        const int slot = g ^ ((f ^ (f >> 2)) & 3);
        boff[ct] = (unsigned)(65536 + f * 64 + slot * 16);
    }

    int cur = 0;
    for (int t = 0; t < 16; ++t) {
        if (t < 15) asm volatile("s_waitcnt vmcnt(2)" ::: "memory");
        else        asm volatile("s_waitcnt vmcnt(0)" ::: "memory");
        __builtin_amdgcn_s_barrier();
        __builtin_amdgcn_sched_barrier(0);
        asm volatile("" ::: "memory");
        if (t < 14) {
            int nb = cur + 2; if (nb >= 3) nb -= 3;
            gll16(gH + (t + 2) * 32, ldsH + nb * 32768);
            gll16(gL + (t + 2) * 32, ldsL + nb * 32768);
        }
        s16x8 bh[4], bl[4];
        #pragma unroll
        for (int ct = 0; ct < 4; ++ct) {
            const unsigned off = boff[ct] + (unsigned)(cur * 32768);
            bh[ct] = *(const s16x8*)(smem + off);
            bl[ct] = *(const s16x8*)(smem + off + 16384);
        }
        const unsigned aoff = abase + ((((unsigned)(t * 4 + g)) * 16) ^ aswz);
        const s16x8 a = *(const s16x8*)(smem + aoff);
        __builtin_amdgcn_s_setprio(1);
        #pragma unroll
        for (int ct = 0; ct < 4; ++ct) {
            acc[ct] = mfma16(a, bh[ct], acc[ct]);
            acc[ct] = mfma16(a, bl[ct], acc[ct]);
        }
        __builtin_amdgcn_s_setprio(0);
        cur = cur + 1; if (cur == 3) cur = 0;
    }

    // epilogue: elu, store (P already normalized)
    #pragma unroll
    for (int ct = 0; ct < 4; ++ct) {
        const int f = wc * 64 + ct * 16 + fb;
        #pragma unroll
        for (int r = 0; r < 4; ++r) {
            float v = acc[ct][r];
            v = (v > 0.f) ? v : expm1f(v);
            const size_t o = ((size_t)bn * NODES + i0 + wr * 16 + g * 4 + r) * FDIM + f;
            if (flag) ((float*)out)[o] = v;
            else      ((unsigned short*)out)[o] = f2bfu(v);
        }
    }
}

extern "C" void kernel_launch(void* const* d_in, const int* in_sizes, int n_in,
                              void* d_out, int out_size, void* d_ws, size_t ws_size,
                              hipStream_t stream)
{
    const void* h   = d_in[0];
    const int*  adj = (const int*)d_in[1];
    const void* W   = d_in[2];
    const void* a   = d_in[3];

    // ws layout: flag 256B | src 128K | dst 128K | WtHi 128K | WtLo 128K
    //            | WhTHi 16.78M | WhTLo 16.78M   (~34.1 MB total)
    int*   flag  = (int*)d_ws;
    float* srcv  = (float*)d_ws + 64;
    float* dstv  = srcv + BN * NODES;
    short* WtHi  = (short*)(dstv + BN * NODES);
    short* WtLo  = WtHi + FDIM * FDIM;
    short* WhTHi = WtLo + FDIM * FDIM;
    short* WhTLo = WhTHi + (size_t)BN * FDIM * NODES;

    detect_kernel<<<1, 256, 0, stream>>>((const unsigned short*)h, flag);
    prep_w_kernel<<<dim3(16, 16), 256, 0, stream>>>(W, flag, WtHi, WtLo);
    wh_gemm<<<512, 256, 0, stream>>>(h, WtHi, WtLo, a, flag,
                                     WhTHi, WhTLo, srcv, dstv);
    pv_gemm<<<512, 1024, 0, stream>>>(WhTHi, WhTLo, srcv, dstv, adj, flag, d_out);
}